// Round 6
// baseline (1988.188 us; speedup 1.0000x reference)
//
#include <hip/hip_runtime.h>
#include <cstdint>
#include <cstddef>

#define NN 100000
#define BSHIFT 9
#define NBUK ((NN + 511) >> 9)   // 196
#define NB_PART 256
#define PART_T 256

typedef __attribute__((ext_vector_type(4))) float f32x4;
typedef __attribute__((ext_vector_type(8))) short bf16x8;
typedef __attribute__((ext_vector_type(8))) _Float16 f16x8;

__device__ __forceinline__ unsigned short f2bf(float x) {
    unsigned int u = __builtin_bit_cast(unsigned int, x);
    unsigned int r = (u + 0x7fffu + ((u >> 16) & 1u)) >> 16;
    return (unsigned short)r;
}

// deg_inv_sqrt with self-loop (+1)
__global__ void dis_kernel(const int* __restrict__ cnt, float* __restrict__ dis, int N) {
    int i = blockIdx.x * blockDim.x + threadIdx.x;
    if (i < N) dis[i] = rsqrtf((float)(cnt[i] + 1));
}

// ---- multi-block exclusive scan over node counts -> rowptr ---------
#define SCAN_B 128
#define SCAN_T 256
#define SCAN_CH 4  // 128*256*4 = 131072 >= NN

__global__ __launch_bounds__(SCAN_T) void scan_part_kernel(const int* __restrict__ cnt,
                                                           int* __restrict__ bsum, int N) {
    __shared__ int s[SCAN_T];
    int b = blockIdx.x, t = threadIdx.x;
    int base = b * SCAN_T * SCAN_CH + t * SCAN_CH;
    int sum = 0;
#pragma unroll
    for (int j = 0; j < SCAN_CH; ++j) {
        int i = base + j;
        if (i < N) sum += cnt[i];
    }
    s[t] = sum;
    __syncthreads();
    for (int off = SCAN_T / 2; off > 0; off >>= 1) {
        if (t < off) s[t] += s[t + off];
        __syncthreads();
    }
    if (t == 0) bsum[b] = s[0];
}

__global__ __launch_bounds__(SCAN_B) void scan_bsum_kernel(const int* __restrict__ bsum,
                                                           int* __restrict__ bofs) {
    __shared__ int s[SCAN_B];
    int t = threadIdx.x;
    int v = bsum[t];
    s[t] = v;
    __syncthreads();
    for (int off = 1; off < SCAN_B; off <<= 1) {
        int x = (t >= off) ? s[t - off] : 0;
        __syncthreads();
        s[t] += x;
        __syncthreads();
    }
    bofs[t] = s[t] - v;  // exclusive
}

__global__ __launch_bounds__(SCAN_T) void scan_write_kernel(const int* __restrict__ cnt,
                                                            const int* __restrict__ bofs,
                                                            int* __restrict__ rowptr,
                                                            int N, int E) {
    __shared__ int s[SCAN_T];
    int b = blockIdx.x, t = threadIdx.x;
    int base = b * SCAN_T * SCAN_CH + t * SCAN_CH;
    int loc[SCAN_CH];
    int sum = 0;
#pragma unroll
    for (int j = 0; j < SCAN_CH; ++j) {
        int i = base + j;
        int c = (i < N) ? cnt[i] : 0;
        loc[j] = c;
        sum += c;
    }
    s[t] = sum;
    __syncthreads();
    for (int off = 1; off < SCAN_T; off <<= 1) {
        int x = (t >= off) ? s[t - off] : 0;
        __syncthreads();
        s[t] += x;
        __syncthreads();
    }
    int run = bofs[b] + s[t] - sum;
#pragma unroll
    for (int j = 0; j < SCAN_CH; ++j) {
        int i = base + j;
        if (i < N) {
            rowptr[i] = run;
            run += loc[j];
        }
    }
    if (b == 0 && t == 0) rowptr[N] = E;
}

// ---- 2-level counting sort (bucket partition, line-dense writes) ----
__global__ __launch_bounds__(PART_T) void part_count_kernel(const int* __restrict__ ecol,
                                                            int* __restrict__ blockcnt, int E) {
    __shared__ int hist[NBUK];
    int b = blockIdx.x, t = threadIdx.x;
    for (int i = t; i < NBUK; i += PART_T) hist[i] = 0;
    __syncthreads();
    int CH = (E + NB_PART - 1) / NB_PART;
    int lo = b * CH;
    int hi = lo + CH; if (hi > E) hi = E;
    for (int e = lo + t; e < hi; e += PART_T)
        atomicAdd(&hist[ecol[e] >> BSHIFT], 1);
    __syncthreads();
    for (int i = t; i < NBUK; i += PART_T) blockcnt[i * NB_PART + b] = hist[i];
}

__global__ __launch_bounds__(NB_PART) void part_scan_kernel(const int* __restrict__ blockcnt,
                                                            int* __restrict__ boffrel,
                                                            int* __restrict__ buktot) {
    __shared__ int s[NB_PART];
    int k = blockIdx.x, t = threadIdx.x;
    int v = blockcnt[k * NB_PART + t];
    s[t] = v;
    __syncthreads();
    for (int off = 1; off < NB_PART; off <<= 1) {
        int x = (t >= off) ? s[t - off] : 0;
        __syncthreads();
        s[t] += x;
        __syncthreads();
    }
    boffrel[k * NB_PART + t] = s[t] - v;  // exclusive, bucket-relative
    if (t == NB_PART - 1) buktot[k] = s[t];
}

__global__ __launch_bounds__(256) void buk_scan_kernel(const int* __restrict__ buktot,
                                                       int* __restrict__ bukbase) {
    __shared__ int s[256];
    int t = threadIdx.x;
    int v = (t < NBUK) ? buktot[t] : 0;
    s[t] = v;
    __syncthreads();
    for (int off = 1; off < 256; off <<= 1) {
        int x = (t >= off) ? s[t - off] : 0;
        __syncthreads();
        s[t] += x;
        __syncthreads();
    }
    if (t < NBUK) bukbase[t] = s[t] - v;  // exclusive
}

__global__ __launch_bounds__(PART_T) void part_write_kernel(const int* __restrict__ erow,
                                                            const int* __restrict__ ecol,
                                                            const int* __restrict__ boffrel,
                                                            const int* __restrict__ bukbase,
                                                            unsigned int* __restrict__ staging, int E) {
    __shared__ int lofs[NBUK];
    int b = blockIdx.x, t = threadIdx.x;
    for (int i = t; i < NBUK; i += PART_T) lofs[i] = bukbase[i] + boffrel[i * NB_PART + b];
    __syncthreads();
    int CH = (E + NB_PART - 1) / NB_PART;
    int lo = b * CH;
    int hi = lo + CH; if (hi > E) hi = E;
    for (int e = lo + t; e < hi; e += PART_T) {
        int c = ecol[e], r = erow[e];
        int k = c >> BSHIFT;
        int pos = atomicAdd(&lofs[k], 1);
        staging[pos] = (unsigned)r | ((unsigned)(c & 511) << 20);
    }
}

__global__ __launch_bounds__(512) void buk_nodecount_kernel(const unsigned int* __restrict__ staging,
                                                            const int* __restrict__ bukbase,
                                                            const int* __restrict__ buktot,
                                                            int* __restrict__ cnt, int N) {
    __shared__ int hist[512];
    int k = blockIdx.x, t = threadIdx.x;
    hist[t] = 0;
    __syncthreads();
    int lo = bukbase[k];
    int hi = lo + buktot[k];
    for (int e = lo + t; e < hi; e += 512)
        atomicAdd(&hist[staging[e] >> 20], 1);
    __syncthreads();
    int node = (k << BSHIFT) + t;
    if (node < N) cnt[node] = hist[t];
}

__global__ __launch_bounds__(512) void part_scatter_kernel(const unsigned int* __restrict__ staging,
                                                           const int* __restrict__ rowptr,
                                                           int* __restrict__ srcs, int N, int E) {
    __shared__ int lnxt[512];
    int k = blockIdx.x, t = threadIdx.x;
    int base = k << BSHIFT;
    int node = base + t;
    lnxt[t] = (node < N) ? rowptr[node] : 0;
    __syncthreads();
    int estart = rowptr[base];
    int hiidx = base + 512; if (hiidx > N) hiidx = N;
    int eend = rowptr[hiidx];
    for (int e = estart + t; e < eend; e += 512) {
        unsigned v = staging[e];
        int p = atomicAdd(&lnxt[v >> 20], 1);
        srcs[p] = (int)(v & 0xFFFFFu);
    }
}

// ------------------------------------------------------------------
// bf16 conversion (n must be a multiple of 8)
__global__ void cvt_bf16_kernel(const float* __restrict__ in, unsigned short* __restrict__ out,
                                size_t n) {
    size_t i = ((size_t)blockIdx.x * blockDim.x + threadIdx.x) * 8;
    size_t stride = (size_t)gridDim.x * blockDim.x * 8;
    for (; i < n; i += stride) {
        float4 a = *(const float4*)(in + i);
        float4 b = *(const float4*)(in + i + 4);
        union { unsigned short u[8]; uint4 v; } r;
        r.u[0] = f2bf(a.x); r.u[1] = f2bf(a.y); r.u[2] = f2bf(a.z); r.u[3] = f2bf(a.w);
        r.u[4] = f2bf(b.x); r.u[5] = f2bf(b.y); r.u[6] = f2bf(b.z); r.u[7] = f2bf(b.w);
        *(uint4*)(out + i) = r.v;
    }
}

// W [K][N] f32 -> Wt [Npad][K] bf16 (transpose + convert, zero-pad rows)
__global__ void wt_cvt_kernel(const float* __restrict__ W, unsigned short* __restrict__ Wt,
                              int K, int N, int Npad) {
    int idx = blockIdx.x * blockDim.x + threadIdx.x;
    int total = Npad * K;
    if (idx >= total) return;
    int n = idx / K, k = idx - n * K;
    float v = (n < N) ? W[(size_t)k * N + n] : 0.f;
    Wt[idx] = f2bf(v);
}

// ------------------------------------------------------------------
// bf16 MFMA GEMM: C = act(A[M,K] @ Bt[N,K]^T + bias)
// FINAL=0: store bf16 C (ldc=N). FINAL=1: store fp16 h16 and u16=dis*h in
// chunk-plane layout [4][M][16] (chunk = col>>4).
template <int RELU, int FINAL>
__global__ __launch_bounds__(256) void gemm_mfma_kernel(
    const unsigned short* __restrict__ A, const unsigned short* __restrict__ Bt,
    const float* __restrict__ bias, unsigned short* __restrict__ Cb,
    _Float16* __restrict__ h16out, _Float16* __restrict__ u16out, const float* __restrict__ dis,
    int M, int K, int N) {
    __shared__ unsigned short sA[128 * 64];
    __shared__ unsigned short sB[128 * 64];
    const int t = threadIdx.x;
    const int wid = t >> 6, lane = t & 63;
    const int bm = blockIdx.x * 128, bn = blockIdx.y * 128;
    const int wr = wid >> 1, wc = wid & 1;

    const int srow = lane >> 3;        // 0..7 row within 8-row group
    const int skb = (lane & 7) * 8;    // bf16-element offset within row (16B granules)

    f32x4 acc[4][4] = {};

    for (int k0 = 0; k0 < K; k0 += 64) {
#pragma unroll
        for (int j = 0; j < 4; ++j) {
            int rbase = (wid * 4 + j) * 8;
            int grow = bm + rbase + srow;
            if (grow >= M) grow = M - 1;
            const unsigned short* asrc = A + (size_t)grow * K + k0 + skb;
            __builtin_amdgcn_global_load_lds(
                (const __attribute__((address_space(1))) unsigned int*)asrc,
                (__attribute__((address_space(3))) unsigned int*)&sA[rbase * 64], 16, 0, 0);
            int gcol = bn + rbase + srow;  // Bt rows are output columns (allocated/padded)
            const unsigned short* bsrc = Bt + (size_t)gcol * K + k0 + skb;
            __builtin_amdgcn_global_load_lds(
                (const __attribute__((address_space(1))) unsigned int*)bsrc,
                (__attribute__((address_space(3))) unsigned int*)&sB[rbase * 64], 16, 0, 0);
        }
        __syncthreads();

        const int fr = lane & 15;
        const int fk = (lane >> 4) * 8;
#pragma unroll
        for (int ks = 0; ks < 2; ++ks) {
            bf16x8 af[4], bfr[4];
#pragma unroll
            for (int m = 0; m < 4; ++m)
                af[m] = *(const bf16x8*)&sA[(wr * 64 + m * 16 + fr) * 64 + ks * 32 + fk];
#pragma unroll
            for (int n = 0; n < 4; ++n)
                bfr[n] = *(const bf16x8*)&sB[(wc * 64 + n * 16 + fr) * 64 + ks * 32 + fk];
#pragma unroll
            for (int m = 0; m < 4; ++m)
#pragma unroll
                for (int n = 0; n < 4; ++n)
                    acc[m][n] = __builtin_amdgcn_mfma_f32_16x16x32_bf16(af[m], bfr[n], acc[m][n], 0, 0, 0);
        }
        __syncthreads();
    }

    const int fr = lane & 15, fq = (lane >> 4) * 4;
#pragma unroll
    for (int m = 0; m < 4; ++m) {
#pragma unroll
        for (int n = 0; n < 4; ++n) {
            int col = bn + wc * 64 + n * 16 + fr;
            if (col >= N) continue;
            float bv = bias[col];
#pragma unroll
            for (int q = 0; q < 4; ++q) {
                int r = bm + wr * 64 + m * 16 + fq + q;
                if (r >= M) continue;
                float v = acc[m][n][q] + bv;
                if (RELU) v = fmaxf(v, 0.f);
                if (!FINAL) {
                    Cb[(size_t)r * N + col] = f2bf(v);
                } else {
                    size_t idx = (size_t)(col >> 4) * ((size_t)M * 16) + (size_t)r * 16 + (col & 15);
                    h16out[idx] = (_Float16)v;
                    u16out[idx] = (_Float16)(dis[r] * v);
                }
            }
        }
    }
}

// ------------------------------------------------------------------
// fp32 fallback GEMM (proven): C = act(A@B + bias)
template <int RELU>
__global__ __launch_bounds__(256) void gemm_bias_kernel(
    const float* __restrict__ A, const float* __restrict__ B,
    const float* __restrict__ bias, float* __restrict__ C,
    int M, int K, int N) {
    __shared__ float sA[16][64];
    __shared__ float sB[16][64];
    const int bm = blockIdx.x * 64;
    const int bn = blockIdx.y * 64;
    const int t = threadIdx.x;
    const int tx = t & 15, ty = t >> 4;
    const int arow_l = t >> 2;
    const int akk = (t & 3) * 4;
    const int brow = t >> 4;
    const int bcol = (t & 15) * 4;
    float acc[4][4] = {};

    for (int k0 = 0; k0 < K; k0 += 16) {
        float4 av = make_float4(0.f, 0.f, 0.f, 0.f);
        int arow = bm + arow_l;
        if (arow < M) av = *(const float4*)(A + (size_t)arow * K + k0 + akk);
        float4 bv = *(const float4*)(B + (size_t)(k0 + brow) * N + bn + bcol);
        sA[akk + 0][arow_l] = av.x;
        sA[akk + 1][arow_l] = av.y;
        sA[akk + 2][arow_l] = av.z;
        sA[akk + 3][arow_l] = av.w;
        *(float4*)&sB[brow][bcol] = bv;
        __syncthreads();
#pragma unroll
        for (int k = 0; k < 16; ++k) {
            float4 a4 = *(const float4*)&sA[k][ty * 4];
            float4 b4 = *(const float4*)&sB[k][tx * 4];
            acc[0][0] += a4.x * b4.x; acc[0][1] += a4.x * b4.y; acc[0][2] += a4.x * b4.z; acc[0][3] += a4.x * b4.w;
            acc[1][0] += a4.y * b4.x; acc[1][1] += a4.y * b4.y; acc[1][2] += a4.y * b4.z; acc[1][3] += a4.y * b4.w;
            acc[2][0] += a4.z * b4.x; acc[2][1] += a4.z * b4.y; acc[2][2] += a4.z * b4.z; acc[2][3] += a4.z * b4.w;
            acc[3][0] += a4.w * b4.x; acc[3][1] += a4.w * b4.y; acc[3][2] += a4.w * b4.z; acc[3][3] += a4.w * b4.w;
        }
        __syncthreads();
    }

#pragma unroll
    for (int i = 0; i < 4; ++i) {
        int row = bm + ty * 4 + i;
        if (row >= M) continue;
#pragma unroll
        for (int j = 0; j < 4; ++j) {
            int colg = bn + tx * 4 + j;
            float v = acc[i][j] + bias[colg];
            if (RELU) v = fmaxf(v, 0.f);
            C[(size_t)row * N + colg] = v;
        }
    }
}

// fallback: h fp32 -> chunked h16, u16 = dis*h
__global__ void h16u0_kernel(const float* __restrict__ h, const float* __restrict__ dis,
                             _Float16* __restrict__ h16, _Float16* __restrict__ u16, int total) {
    int i = blockIdx.x * blockDim.x + threadIdx.x;
    if (i < total) {
        int r = i >> 6, col = i & 63;
        float v = h[i];
        size_t idx = (size_t)(col >> 4) * ((size_t)NN * 16) + (size_t)r * 16 + (col & 15);
        h16[idx] = (_Float16)v;
        u16[idx] = (_Float16)(dis[r] * v);
    }
}

// ------------------------------------------------------------------
// Feature-chunked APPNP step on u = dis*z (fp16 planes [4][NN][16]):
//   S = sum_e u[src];  z' = 0.8*d*(S + u[n]) + 0.2*h
// Wave = (node, chunk). Lane = 32 edge-groups x 2 feature-lanes (16B each).
// Grid is chunk-major: blocks [c*NN/4 .. ) all work on plane c -> plane is
// L2-resident (3.2 MB < 4 MiB/XCD).
// FINAL=0 stores u' = d*z' (fp16 plane); FINAL=1 stores z' (fp32 interleaved out).
template <int FINAL>
__global__ __launch_bounds__(256) void appnp_chunk16_kernel(
    const int* __restrict__ rowptr, const int* __restrict__ srcs,
    const float* __restrict__ dis, const _Float16* __restrict__ uin,
    const _Float16* __restrict__ hbuf, void* __restrict__ outbuf) {
    int unit = blockIdx.x * 4 + (threadIdx.x >> 6);   // chunk*NN + node
    int chunk = unit / NN;
    int node = unit - chunk * NN;
    int lane = threadIdx.x & 63;
    int eg = lane >> 1;   // edge group 0..31
    int fl = lane & 1;    // feature half (8 halves = 16B)

    const _Float16* up = uin + (size_t)chunk * (NN * 16);
    int start = rowptr[node];
    int end = rowptr[node + 1];
    float acc[8] = {};
    for (int e = start + eg; e < end; e += 32) {
        int s = srcs[e];
        f16x8 zv = *(const f16x8*)(up + s * 16 + fl * 8);
#pragma unroll
        for (int j = 0; j < 8; ++j) acc[j] += (float)zv[j];
    }
#pragma unroll
    for (int j = 0; j < 8; ++j) {
        acc[j] += __shfl_xor(acc[j], 2);
        acc[j] += __shfl_xor(acc[j], 4);
        acc[j] += __shfl_xor(acc[j], 8);
        acc[j] += __shfl_xor(acc[j], 16);
        acc[j] += __shfl_xor(acc[j], 32);
    }

    if (eg == 0) {
        float d = dis[node];
        f16x8 us = *(const f16x8*)(up + node * 16 + fl * 8);
        f16x8 hv = *(const f16x8*)(hbuf + (size_t)chunk * (NN * 16) + node * 16 + fl * 8);
        float o[8];
#pragma unroll
        for (int j = 0; j < 8; ++j)
            o[j] = 0.8f * d * (acc[j] + (float)us[j]) + 0.2f * (float)hv[j];
        if (FINAL) {
            float* op = (float*)outbuf + (size_t)node * 64 + chunk * 16 + fl * 8;
            *(float4*)op = make_float4(o[0], o[1], o[2], o[3]);
            *(float4*)(op + 4) = make_float4(o[4], o[5], o[6], o[7]);
        } else {
            f16x8 ov;
#pragma unroll
            for (int j = 0; j < 8; ++j) ov[j] = (_Float16)(d * o[j]);
            *(f16x8*)((_Float16*)outbuf + (size_t)chunk * (NN * 16) + node * 16 + fl * 8) = ov;
        }
    }
}

// ------------------------------------------------------------------
extern "C" void kernel_launch(void* const* d_in, const int* in_sizes, int n_in,
                              void* d_out, int out_size, void* d_ws, size_t ws_size,
                              hipStream_t stream) {
    const float* x  = (const float*)d_in[0];
    const int*   ei = (const int*)d_in[1];
    const float* W0 = (const float*)d_in[2];
    const float* b0 = (const float*)d_in[3];
    const float* W1 = (const float*)d_in[4];
    const float* b1 = (const float*)d_in[5];
    const float* W2 = (const float*)d_in[6];
    const float* b2 = (const float*)d_in[7];
    float* out = (float*)d_out;

    const int N = NN;
    const int E = in_sizes[1] / 2;
    const int* erow = ei;       // sources
    const int* ecol = ei + E;   // targets
    (void)out_size; (void)n_in;

    char* ws = (char*)d_ws;
    size_t off = 0;
    auto alloc = [&](size_t bytes) -> void* {
        void* p = ws + off;
        off += (bytes + 255) & ~(size_t)255;
        return p;
    };
    // common
    int*   cnt      = (int*)alloc((size_t)N * 4);
    int*   rowptr   = (int*)alloc((size_t)(N + 1) * 4);
    float* dis      = (float*)alloc((size_t)N * 4);
    int*   bsum     = (int*)alloc((size_t)SCAN_B * 4);
    int*   bofs     = (int*)alloc((size_t)SCAN_B * 4);
    int*   blockcnt = (int*)alloc((size_t)NBUK * NB_PART * 4);
    int*   boffrel  = (int*)alloc((size_t)NBUK * NB_PART * 4);
    int*   buktot   = (int*)alloc((size_t)NBUK * 4);
    int*   bukbase  = (int*)alloc((size_t)NBUK * 4);
    unsigned int* staging = (unsigned int*)alloc((size_t)E * 4);
    int*   srcs     = (int*)alloc((size_t)E * 4);
    _Float16* h16 = (_Float16*)alloc((size_t)N * 64 * 2);
    _Float16* ua  = (_Float16*)alloc((size_t)N * 64 * 2);
    _Float16* ub  = (_Float16*)alloc((size_t)N * 64 * 2);
    size_t common_end = off;

    // bf16-path extra
    size_t need_bf16 = common_end
        + (((size_t)N * 512 * 2 + 255) & ~(size_t)255)     // xb
        + ((256 * 512 * 2 + 255) & ~(size_t)255)           // Wt0
        + ((256 * 256 * 2 + 255) & ~(size_t)255)           // Wt1
        + ((128 * 256 * 2 + 255) & ~(size_t)255)           // Wt2 (padded)
        + (((size_t)N * 256 * 2 + 255) & ~(size_t)255)     // h1b
        + (((size_t)N * 256 * 2 + 255) & ~(size_t)255);    // h2b
    const bool use_bf16 = (ws_size >= need_bf16 + (1u << 20));

    // ---- 2-level counting sort into CSC (no global atomics on hot paths) ----
    part_count_kernel<<<NB_PART, PART_T, 0, stream>>>(ecol, blockcnt, E);
    part_scan_kernel<<<NBUK, NB_PART, 0, stream>>>(blockcnt, boffrel, buktot);
    buk_scan_kernel<<<1, 256, 0, stream>>>(buktot, bukbase);
    part_write_kernel<<<NB_PART, PART_T, 0, stream>>>(erow, ecol, boffrel, bukbase, staging, E);
    buk_nodecount_kernel<<<NBUK, 512, 0, stream>>>(staging, bukbase, buktot, cnt, N);
    dis_kernel<<<(N + 255) / 256, 256, 0, stream>>>(cnt, dis, N);
    scan_part_kernel<<<SCAN_B, SCAN_T, 0, stream>>>(cnt, bsum, N);
    scan_bsum_kernel<<<1, SCAN_B, 0, stream>>>(bsum, bofs);
    scan_write_kernel<<<SCAN_B, SCAN_T, 0, stream>>>(cnt, bofs, rowptr, N, E);
    part_scatter_kernel<<<NBUK, 512, 0, stream>>>(staging, rowptr, srcs, N, E);

    // ---- MLP -> h16 (chunked fp16) and ua = u0 = dis*h (chunked fp16) ----
    if (use_bf16) {
        unsigned short* xb  = (unsigned short*)alloc((size_t)N * 512 * 2);
        unsigned short* Wt0 = (unsigned short*)alloc(256 * 512 * 2);
        unsigned short* Wt1 = (unsigned short*)alloc(256 * 256 * 2);
        unsigned short* Wt2 = (unsigned short*)alloc(128 * 256 * 2);
        unsigned short* h1b = (unsigned short*)alloc((size_t)N * 256 * 2);
        unsigned short* h2b = (unsigned short*)alloc((size_t)N * 256 * 2);

        cvt_bf16_kernel<<<2048, 256, 0, stream>>>(x, xb, (size_t)N * 512);
        wt_cvt_kernel<<<(256 * 512 + 255) / 256, 256, 0, stream>>>(W0, Wt0, 512, 256, 256);
        wt_cvt_kernel<<<(256 * 256 + 255) / 256, 256, 0, stream>>>(W1, Wt1, 256, 256, 256);
        wt_cvt_kernel<<<(128 * 256 + 255) / 256, 256, 0, stream>>>(W2, Wt2, 256, 64, 128);

        const int gm = (N + 127) / 128;  // 782
        dim3 g0(gm, 2);
        gemm_mfma_kernel<1, 0><<<g0, 256, 0, stream>>>(xb, Wt0, b0, h1b, nullptr, nullptr, nullptr, N, 512, 256);
        gemm_mfma_kernel<1, 0><<<g0, 256, 0, stream>>>(h1b, Wt1, b1, h2b, nullptr, nullptr, nullptr, N, 256, 256);
        dim3 g2(gm, 1);
        gemm_mfma_kernel<0, 1><<<g2, 256, 0, stream>>>(h2b, Wt2, b2, nullptr, h16, ua, dis, N, 256, 64);
    } else {
        const int Ms = 12500;
        float* hf  = (float*)alloc((size_t)N * 64 * 4);
        float* h1s = (float*)alloc((size_t)Ms * 256 * 4);
        float* h2s = (float*)alloc((size_t)Ms * 256 * 4);
        for (int s0 = 0; s0 < N; s0 += Ms) {
            int rows = (N - s0 < Ms) ? (N - s0) : Ms;
            dim3 g1((rows + 63) / 64, 4);
            gemm_bias_kernel<1><<<g1, 256, 0, stream>>>(x + (size_t)s0 * 512, W0, b0, h1s, rows, 512, 256);
            gemm_bias_kernel<1><<<g1, 256, 0, stream>>>(h1s, W1, b1, h2s, rows, 256, 256);
            dim3 g3((rows + 63) / 64, 1);
            gemm_bias_kernel<0><<<g3, 256, 0, stream>>>(h2s, W2, b2, hf + (size_t)s0 * 64, rows, 256, 64);
        }
        h16u0_kernel<<<(N * 64 + 255) / 256, 256, 0, stream>>>(hf, dis, h16, ua, N * 64);
    }

    // ---- APPNP propagation: 10 feature-chunked steps on u (fp16 planes) ----
    const _Float16* uin = ua;
    for (int k = 0; k < 10; ++k) {
        if (k == 9) {
            appnp_chunk16_kernel<1><<<N, 256, 0, stream>>>(rowptr, srcs, dis, uin, h16, out);
        } else {
            _Float16* uout = (k & 1) ? ua : ub;
            appnp_chunk16_kernel<0><<<N, 256, 0, stream>>>(rowptr, srcs, dis, uin, h16, uout);
            uin = uout;
        }
    }
}

// Round 7
// 1186.159 us; speedup vs baseline: 1.6762x; 1.6762x over previous
//
#include <hip/hip_runtime.h>
#include <cstdint>
#include <cstddef>

#define NN 100000
#define BSHIFT 9
#define NBUK ((NN + 511) >> 9)   // 196
#define NB_PART 256
#define PART_T 256

typedef __attribute__((ext_vector_type(4))) float f32x4;
typedef __attribute__((ext_vector_type(8))) short bf16x8;
typedef __attribute__((ext_vector_type(8))) _Float16 f16x8;

__device__ __forceinline__ unsigned short f2bf(float x) {
    unsigned int u = __builtin_bit_cast(unsigned int, x);
    unsigned int r = (u + 0x7fffu + ((u >> 16) & 1u)) >> 16;
    return (unsigned short)r;
}

// deg_inv_sqrt with self-loop (+1)
__global__ void dis_kernel(const int* __restrict__ cnt, float* __restrict__ dis, int N) {
    int i = blockIdx.x * blockDim.x + threadIdx.x;
    if (i < N) dis[i] = rsqrtf((float)(cnt[i] + 1));
}

// ---- multi-block exclusive scan over node counts -> rowptr ---------
#define SCAN_B 128
#define SCAN_T 256
#define SCAN_CH 4  // 128*256*4 = 131072 >= NN

__global__ __launch_bounds__(SCAN_T) void scan_part_kernel(const int* __restrict__ cnt,
                                                           int* __restrict__ bsum, int N) {
    __shared__ int s[SCAN_T];
    int b = blockIdx.x, t = threadIdx.x;
    int base = b * SCAN_T * SCAN_CH + t * SCAN_CH;
    int sum = 0;
#pragma unroll
    for (int j = 0; j < SCAN_CH; ++j) {
        int i = base + j;
        if (i < N) sum += cnt[i];
    }
    s[t] = sum;
    __syncthreads();
    for (int off = SCAN_T / 2; off > 0; off >>= 1) {
        if (t < off) s[t] += s[t + off];
        __syncthreads();
    }
    if (t == 0) bsum[b] = s[0];
}

__global__ __launch_bounds__(SCAN_B) void scan_bsum_kernel(const int* __restrict__ bsum,
                                                           int* __restrict__ bofs) {
    __shared__ int s[SCAN_B];
    int t = threadIdx.x;
    int v = bsum[t];
    s[t] = v;
    __syncthreads();
    for (int off = 1; off < SCAN_B; off <<= 1) {
        int x = (t >= off) ? s[t - off] : 0;
        __syncthreads();
        s[t] += x;
        __syncthreads();
    }
    bofs[t] = s[t] - v;  // exclusive
}

__global__ __launch_bounds__(SCAN_T) void scan_write_kernel(const int* __restrict__ cnt,
                                                            const int* __restrict__ bofs,
                                                            int* __restrict__ rowptr,
                                                            int N, int E) {
    __shared__ int s[SCAN_T];
    int b = blockIdx.x, t = threadIdx.x;
    int base = b * SCAN_T * SCAN_CH + t * SCAN_CH;
    int loc[SCAN_CH];
    int sum = 0;
#pragma unroll
    for (int j = 0; j < SCAN_CH; ++j) {
        int i = base + j;
        int c = (i < N) ? cnt[i] : 0;
        loc[j] = c;
        sum += c;
    }
    s[t] = sum;
    __syncthreads();
    for (int off = 1; off < SCAN_T; off <<= 1) {
        int x = (t >= off) ? s[t - off] : 0;
        __syncthreads();
        s[t] += x;
        __syncthreads();
    }
    int run = bofs[b] + s[t] - sum;
#pragma unroll
    for (int j = 0; j < SCAN_CH; ++j) {
        int i = base + j;
        if (i < N) {
            rowptr[i] = run;
            run += loc[j];
        }
    }
    if (b == 0 && t == 0) rowptr[N] = E;
}

// ---- 2-level counting sort (bucket partition, line-dense writes) ----
__global__ __launch_bounds__(PART_T) void part_count_kernel(const int* __restrict__ ecol,
                                                            int* __restrict__ blockcnt, int E) {
    __shared__ int hist[NBUK];
    int b = blockIdx.x, t = threadIdx.x;
    for (int i = t; i < NBUK; i += PART_T) hist[i] = 0;
    __syncthreads();
    int CH = (E + NB_PART - 1) / NB_PART;
    int lo = b * CH;
    int hi = lo + CH; if (hi > E) hi = E;
    for (int e = lo + t; e < hi; e += PART_T)
        atomicAdd(&hist[ecol[e] >> BSHIFT], 1);
    __syncthreads();
    for (int i = t; i < NBUK; i += PART_T) blockcnt[i * NB_PART + b] = hist[i];
}

__global__ __launch_bounds__(NB_PART) void part_scan_kernel(const int* __restrict__ blockcnt,
                                                            int* __restrict__ boffrel,
                                                            int* __restrict__ buktot) {
    __shared__ int s[NB_PART];
    int k = blockIdx.x, t = threadIdx.x;
    int v = blockcnt[k * NB_PART + t];
    s[t] = v;
    __syncthreads();
    for (int off = 1; off < NB_PART; off <<= 1) {
        int x = (t >= off) ? s[t - off] : 0;
        __syncthreads();
        s[t] += x;
        __syncthreads();
    }
    boffrel[k * NB_PART + t] = s[t] - v;  // exclusive, bucket-relative
    if (t == NB_PART - 1) buktot[k] = s[t];
}

__global__ __launch_bounds__(256) void buk_scan_kernel(const int* __restrict__ buktot,
                                                       int* __restrict__ bukbase) {
    __shared__ int s[256];
    int t = threadIdx.x;
    int v = (t < NBUK) ? buktot[t] : 0;
    s[t] = v;
    __syncthreads();
    for (int off = 1; off < 256; off <<= 1) {
        int x = (t >= off) ? s[t - off] : 0;
        __syncthreads();
        s[t] += x;
        __syncthreads();
    }
    if (t < NBUK) bukbase[t] = s[t] - v;  // exclusive
}

__global__ __launch_bounds__(PART_T) void part_write_kernel(const int* __restrict__ erow,
                                                            const int* __restrict__ ecol,
                                                            const int* __restrict__ boffrel,
                                                            const int* __restrict__ bukbase,
                                                            unsigned int* __restrict__ staging, int E) {
    __shared__ int lofs[NBUK];
    int b = blockIdx.x, t = threadIdx.x;
    for (int i = t; i < NBUK; i += PART_T) lofs[i] = bukbase[i] + boffrel[i * NB_PART + b];
    __syncthreads();
    int CH = (E + NB_PART - 1) / NB_PART;
    int lo = b * CH;
    int hi = lo + CH; if (hi > E) hi = E;
    for (int e = lo + t; e < hi; e += PART_T) {
        int c = ecol[e], r = erow[e];
        int k = c >> BSHIFT;
        int pos = atomicAdd(&lofs[k], 1);
        staging[pos] = (unsigned)r | ((unsigned)(c & 511) << 20);
    }
}

__global__ __launch_bounds__(512) void buk_nodecount_kernel(const unsigned int* __restrict__ staging,
                                                            const int* __restrict__ bukbase,
                                                            const int* __restrict__ buktot,
                                                            int* __restrict__ cnt, int N) {
    __shared__ int hist[512];
    int k = blockIdx.x, t = threadIdx.x;
    hist[t] = 0;
    __syncthreads();
    int lo = bukbase[k];
    int hi = lo + buktot[k];
    for (int e = lo + t; e < hi; e += 512)
        atomicAdd(&hist[staging[e] >> 20], 1);
    __syncthreads();
    int node = (k << BSHIFT) + t;
    if (node < N) cnt[node] = hist[t];
}

__global__ __launch_bounds__(512) void part_scatter_kernel(const unsigned int* __restrict__ staging,
                                                           const int* __restrict__ rowptr,
                                                           int* __restrict__ srcs, int N, int E) {
    __shared__ int lnxt[512];
    int k = blockIdx.x, t = threadIdx.x;
    int base = k << BSHIFT;
    int node = base + t;
    lnxt[t] = (node < N) ? rowptr[node] : 0;
    __syncthreads();
    int estart = rowptr[base];
    int hiidx = base + 512; if (hiidx > N) hiidx = N;
    int eend = rowptr[hiidx];
    for (int e = estart + t; e < eend; e += 512) {
        unsigned v = staging[e];
        int p = atomicAdd(&lnxt[v >> 20], 1);
        srcs[p] = (int)(v & 0xFFFFFu);
    }
}

// ------------------------------------------------------------------
// bf16 conversion (n must be a multiple of 8)
__global__ void cvt_bf16_kernel(const float* __restrict__ in, unsigned short* __restrict__ out,
                                size_t n) {
    size_t i = ((size_t)blockIdx.x * blockDim.x + threadIdx.x) * 8;
    size_t stride = (size_t)gridDim.x * blockDim.x * 8;
    for (; i < n; i += stride) {
        float4 a = *(const float4*)(in + i);
        float4 b = *(const float4*)(in + i + 4);
        union { unsigned short u[8]; uint4 v; } r;
        r.u[0] = f2bf(a.x); r.u[1] = f2bf(a.y); r.u[2] = f2bf(a.z); r.u[3] = f2bf(a.w);
        r.u[4] = f2bf(b.x); r.u[5] = f2bf(b.y); r.u[6] = f2bf(b.z); r.u[7] = f2bf(b.w);
        *(uint4*)(out + i) = r.v;
    }
}

// W [K][N] f32 -> Wt [Npad][K] bf16 (transpose + convert, zero-pad rows)
__global__ void wt_cvt_kernel(const float* __restrict__ W, unsigned short* __restrict__ Wt,
                              int K, int N, int Npad) {
    int idx = blockIdx.x * blockDim.x + threadIdx.x;
    int total = Npad * K;
    if (idx >= total) return;
    int n = idx / K, k = idx - n * K;
    float v = (n < N) ? W[(size_t)k * N + n] : 0.f;
    Wt[idx] = f2bf(v);
}

// ------------------------------------------------------------------
// bf16 MFMA GEMM: C = act(A[M,K] @ Bt[N,K]^T + bias)
// FINAL=0: store bf16 C (ldc=N). FINAL=1: store fp16 h16 and u16=dis*h in
// chunk-plane layout [4][M][16] (chunk = col>>4).
template <int RELU, int FINAL>
__global__ __launch_bounds__(256) void gemm_mfma_kernel(
    const unsigned short* __restrict__ A, const unsigned short* __restrict__ Bt,
    const float* __restrict__ bias, unsigned short* __restrict__ Cb,
    _Float16* __restrict__ h16out, _Float16* __restrict__ u16out, const float* __restrict__ dis,
    int M, int K, int N) {
    __shared__ unsigned short sA[128 * 64];
    __shared__ unsigned short sB[128 * 64];
    const int t = threadIdx.x;
    const int wid = t >> 6, lane = t & 63;
    const int bm = blockIdx.x * 128, bn = blockIdx.y * 128;
    const int wr = wid >> 1, wc = wid & 1;

    const int srow = lane >> 3;        // 0..7 row within 8-row group
    const int skb = (lane & 7) * 8;    // bf16-element offset within row (16B granules)

    f32x4 acc[4][4] = {};

    for (int k0 = 0; k0 < K; k0 += 64) {
#pragma unroll
        for (int j = 0; j < 4; ++j) {
            int rbase = (wid * 4 + j) * 8;
            int grow = bm + rbase + srow;
            if (grow >= M) grow = M - 1;
            const unsigned short* asrc = A + (size_t)grow * K + k0 + skb;
            __builtin_amdgcn_global_load_lds(
                (const __attribute__((address_space(1))) unsigned int*)asrc,
                (__attribute__((address_space(3))) unsigned int*)&sA[rbase * 64], 16, 0, 0);
            int gcol = bn + rbase + srow;  // Bt rows are output columns (allocated/padded)
            const unsigned short* bsrc = Bt + (size_t)gcol * K + k0 + skb;
            __builtin_amdgcn_global_load_lds(
                (const __attribute__((address_space(1))) unsigned int*)bsrc,
                (__attribute__((address_space(3))) unsigned int*)&sB[rbase * 64], 16, 0, 0);
        }
        __syncthreads();

        const int fr = lane & 15;
        const int fk = (lane >> 4) * 8;
#pragma unroll
        for (int ks = 0; ks < 2; ++ks) {
            bf16x8 af[4], bfr[4];
#pragma unroll
            for (int m = 0; m < 4; ++m)
                af[m] = *(const bf16x8*)&sA[(wr * 64 + m * 16 + fr) * 64 + ks * 32 + fk];
#pragma unroll
            for (int n = 0; n < 4; ++n)
                bfr[n] = *(const bf16x8*)&sB[(wc * 64 + n * 16 + fr) * 64 + ks * 32 + fk];
#pragma unroll
            for (int m = 0; m < 4; ++m)
#pragma unroll
                for (int n = 0; n < 4; ++n)
                    acc[m][n] = __builtin_amdgcn_mfma_f32_16x16x32_bf16(af[m], bfr[n], acc[m][n], 0, 0, 0);
        }
        __syncthreads();
    }

    const int fr = lane & 15, fq = (lane >> 4) * 4;
#pragma unroll
    for (int m = 0; m < 4; ++m) {
#pragma unroll
        for (int n = 0; n < 4; ++n) {
            int col = bn + wc * 64 + n * 16 + fr;
            if (col >= N) continue;
            float bv = bias[col];
#pragma unroll
            for (int q = 0; q < 4; ++q) {
                int r = bm + wr * 64 + m * 16 + fq + q;
                if (r >= M) continue;
                float v = acc[m][n][q] + bv;
                if (RELU) v = fmaxf(v, 0.f);
                if (!FINAL) {
                    Cb[(size_t)r * N + col] = f2bf(v);
                } else {
                    size_t idx = (size_t)(col >> 4) * ((size_t)M * 16) + (size_t)r * 16 + (col & 15);
                    h16out[idx] = (_Float16)v;
                    u16out[idx] = (_Float16)(dis[r] * v);
                }
            }
        }
    }
}

// ------------------------------------------------------------------
// fp32 fallback GEMM (proven): C = act(A@B + bias)
template <int RELU>
__global__ __launch_bounds__(256) void gemm_bias_kernel(
    const float* __restrict__ A, const float* __restrict__ B,
    const float* __restrict__ bias, float* __restrict__ C,
    int M, int K, int N) {
    __shared__ float sA[16][64];
    __shared__ float sB[16][64];
    const int bm = blockIdx.x * 64;
    const int bn = blockIdx.y * 64;
    const int t = threadIdx.x;
    const int tx = t & 15, ty = t >> 4;
    const int arow_l = t >> 2;
    const int akk = (t & 3) * 4;
    const int brow = t >> 4;
    const int bcol = (t & 15) * 4;
    float acc[4][4] = {};

    for (int k0 = 0; k0 < K; k0 += 16) {
        float4 av = make_float4(0.f, 0.f, 0.f, 0.f);
        int arow = bm + arow_l;
        if (arow < M) av = *(const float4*)(A + (size_t)arow * K + k0 + akk);
        float4 bv = *(const float4*)(B + (size_t)(k0 + brow) * N + bn + bcol);
        sA[akk + 0][arow_l] = av.x;
        sA[akk + 1][arow_l] = av.y;
        sA[akk + 2][arow_l] = av.z;
        sA[akk + 3][arow_l] = av.w;
        *(float4*)&sB[brow][bcol] = bv;
        __syncthreads();
#pragma unroll
        for (int k = 0; k < 16; ++k) {
            float4 a4 = *(const float4*)&sA[k][ty * 4];
            float4 b4 = *(const float4*)&sB[k][tx * 4];
            acc[0][0] += a4.x * b4.x; acc[0][1] += a4.x * b4.y; acc[0][2] += a4.x * b4.z; acc[0][3] += a4.x * b4.w;
            acc[1][0] += a4.y * b4.x; acc[1][1] += a4.y * b4.y; acc[1][2] += a4.y * b4.z; acc[1][3] += a4.y * b4.w;
            acc[2][0] += a4.z * b4.x; acc[2][1] += a4.z * b4.y; acc[2][2] += a4.z * b4.z; acc[2][3] += a4.z * b4.w;
            acc[3][0] += a4.w * b4.x; acc[3][1] += a4.w * b4.y; acc[3][2] += a4.w * b4.z; acc[3][3] += a4.w * b4.w;
        }
        __syncthreads();
    }

#pragma unroll
    for (int i = 0; i < 4; ++i) {
        int row = bm + ty * 4 + i;
        if (row >= M) continue;
#pragma unroll
        for (int j = 0; j < 4; ++j) {
            int colg = bn + tx * 4 + j;
            float v = acc[i][j] + bias[colg];
            if (RELU) v = fmaxf(v, 0.f);
            C[(size_t)row * N + colg] = v;
        }
    }
}

// fallback: h fp32 -> chunked h16, u16 = dis*h
__global__ void h16u0_kernel(const float* __restrict__ h, const float* __restrict__ dis,
                             _Float16* __restrict__ h16, _Float16* __restrict__ u16, int total) {
    int i = blockIdx.x * blockDim.x + threadIdx.x;
    if (i < total) {
        int r = i >> 6, col = i & 63;
        float v = h[i];
        size_t idx = (size_t)(col >> 4) * ((size_t)NN * 16) + (size_t)r * 16 + (col & 15);
        h16[idx] = (_Float16)v;
        u16[idx] = (_Float16)(dis[r] * v);
    }
}

// ------------------------------------------------------------------
// Feature-plane APPNP step on u = dis*z (fp16 planes [4][NN][16]):
//   S = sum_e u[src];  z' = 0.8*d*(S + u[n]) + 0.2*h
// Wave = 4 nodes x 16 lanes; per node: 8 edge-groups x 2 feature-lanes (16B).
// Per-node instruction economy identical to the proven interleaved kernel;
// only the gather target shrinks to a 3.2MB L2-resident plane.
// Grid dim3(NN/16, 4): blockIdx.y = chunk (chunk-major dispatch).
// FINAL=0 stores u' = d*z' (fp16 plane); FINAL=1 stores z' (fp32 interleaved).
template <int FINAL>
__global__ __launch_bounds__(256) void appnp_plane16_kernel(
    const int* __restrict__ rowptr, const int* __restrict__ srcs,
    const float* __restrict__ dis, const _Float16* __restrict__ uin,
    const _Float16* __restrict__ hbuf, void* __restrict__ outbuf) {
    const int chunk = blockIdx.y;
    const int node = blockIdx.x * 16 + (threadIdx.x >> 4);
    const int l = threadIdx.x & 15;
    const int eg = l >> 1;   // edge group 0..7
    const int fl = l & 1;    // feature half (8 halves = 16B)

    const _Float16* up = uin + (size_t)chunk * (NN * 16);
    int start = rowptr[node];
    int end = rowptr[node + 1];
    float acc[8] = {};
    for (int e = start + eg; e < end; e += 8) {
        int s = srcs[e];
        f16x8 zv = *(const f16x8*)(up + s * 16 + fl * 8);
#pragma unroll
        for (int j = 0; j < 8; ++j) acc[j] += (float)zv[j];
    }
    // reduce across the 8 edge groups (bits 1..3 of lane) — stays in subgroup
#pragma unroll
    for (int j = 0; j < 8; ++j) {
        acc[j] += __shfl_xor(acc[j], 2);
        acc[j] += __shfl_xor(acc[j], 4);
        acc[j] += __shfl_xor(acc[j], 8);
    }

    if (eg == 0) {
        float d = dis[node];
        f16x8 us = *(const f16x8*)(up + (size_t)node * 16 + fl * 8);
        f16x8 hv = *(const f16x8*)(hbuf + (size_t)chunk * (NN * 16) + (size_t)node * 16 + fl * 8);
        float o[8];
#pragma unroll
        for (int j = 0; j < 8; ++j)
            o[j] = 0.8f * d * (acc[j] + (float)us[j]) + 0.2f * (float)hv[j];
        if (FINAL) {
            float* op = (float*)outbuf + (size_t)node * 64 + chunk * 16 + fl * 8;
            *(float4*)op = make_float4(o[0], o[1], o[2], o[3]);
            *(float4*)(op + 4) = make_float4(o[4], o[5], o[6], o[7]);
        } else {
            f16x8 ov;
#pragma unroll
            for (int j = 0; j < 8; ++j) ov[j] = (_Float16)(d * o[j]);
            *(f16x8*)((_Float16*)outbuf + (size_t)chunk * (NN * 16) + (size_t)node * 16 + fl * 8) = ov;
        }
    }
}

// ------------------------------------------------------------------
extern "C" void kernel_launch(void* const* d_in, const int* in_sizes, int n_in,
                              void* d_out, int out_size, void* d_ws, size_t ws_size,
                              hipStream_t stream) {
    const float* x  = (const float*)d_in[0];
    const int*   ei = (const int*)d_in[1];
    const float* W0 = (const float*)d_in[2];
    const float* b0 = (const float*)d_in[3];
    const float* W1 = (const float*)d_in[4];
    const float* b1 = (const float*)d_in[5];
    const float* W2 = (const float*)d_in[6];
    const float* b2 = (const float*)d_in[7];
    float* out = (float*)d_out;

    const int N = NN;
    const int E = in_sizes[1] / 2;
    const int* erow = ei;       // sources
    const int* ecol = ei + E;   // targets
    (void)out_size; (void)n_in;

    char* ws = (char*)d_ws;
    size_t off = 0;
    auto alloc = [&](size_t bytes) -> void* {
        void* p = ws + off;
        off += (bytes + 255) & ~(size_t)255;
        return p;
    };
    // common
    int*   cnt      = (int*)alloc((size_t)N * 4);
    int*   rowptr   = (int*)alloc((size_t)(N + 1) * 4);
    float* dis      = (float*)alloc((size_t)N * 4);
    int*   bsum     = (int*)alloc((size_t)SCAN_B * 4);
    int*   bofs     = (int*)alloc((size_t)SCAN_B * 4);
    int*   blockcnt = (int*)alloc((size_t)NBUK * NB_PART * 4);
    int*   boffrel  = (int*)alloc((size_t)NBUK * NB_PART * 4);
    int*   buktot   = (int*)alloc((size_t)NBUK * 4);
    int*   bukbase  = (int*)alloc((size_t)NBUK * 4);
    unsigned int* staging = (unsigned int*)alloc((size_t)E * 4);
    int*   srcs     = (int*)alloc((size_t)E * 4);
    _Float16* h16 = (_Float16*)alloc((size_t)N * 64 * 2);
    _Float16* ua  = (_Float16*)alloc((size_t)N * 64 * 2);
    _Float16* ub  = (_Float16*)alloc((size_t)N * 64 * 2);
    size_t common_end = off;

    // bf16-path extra
    size_t need_bf16 = common_end
        + (((size_t)N * 512 * 2 + 255) & ~(size_t)255)     // xb
        + ((256 * 512 * 2 + 255) & ~(size_t)255)           // Wt0
        + ((256 * 256 * 2 + 255) & ~(size_t)255)           // Wt1
        + ((128 * 256 * 2 + 255) & ~(size_t)255)           // Wt2 (padded)
        + (((size_t)N * 256 * 2 + 255) & ~(size_t)255)     // h1b
        + (((size_t)N * 256 * 2 + 255) & ~(size_t)255);    // h2b
    const bool use_bf16 = (ws_size >= need_bf16 + (1u << 20));

    // ---- 2-level counting sort into CSC (no global atomics on hot paths) ----
    part_count_kernel<<<NB_PART, PART_T, 0, stream>>>(ecol, blockcnt, E);
    part_scan_kernel<<<NBUK, NB_PART, 0, stream>>>(blockcnt, boffrel, buktot);
    buk_scan_kernel<<<1, 256, 0, stream>>>(buktot, bukbase);
    part_write_kernel<<<NB_PART, PART_T, 0, stream>>>(erow, ecol, boffrel, bukbase, staging, E);
    buk_nodecount_kernel<<<NBUK, 512, 0, stream>>>(staging, bukbase, buktot, cnt, N);
    dis_kernel<<<(N + 255) / 256, 256, 0, stream>>>(cnt, dis, N);
    scan_part_kernel<<<SCAN_B, SCAN_T, 0, stream>>>(cnt, bsum, N);
    scan_bsum_kernel<<<1, SCAN_B, 0, stream>>>(bsum, bofs);
    scan_write_kernel<<<SCAN_B, SCAN_T, 0, stream>>>(cnt, bofs, rowptr, N, E);
    part_scatter_kernel<<<NBUK, 512, 0, stream>>>(staging, rowptr, srcs, N, E);

    // ---- MLP -> h16 (chunked fp16) and ua = u0 = dis*h (chunked fp16) ----
    if (use_bf16) {
        unsigned short* xb  = (unsigned short*)alloc((size_t)N * 512 * 2);
        unsigned short* Wt0 = (unsigned short*)alloc(256 * 512 * 2);
        unsigned short* Wt1 = (unsigned short*)alloc(256 * 256 * 2);
        unsigned short* Wt2 = (unsigned short*)alloc(128 * 256 * 2);
        unsigned short* h1b = (unsigned short*)alloc((size_t)N * 256 * 2);
        unsigned short* h2b = (unsigned short*)alloc((size_t)N * 256 * 2);

        cvt_bf16_kernel<<<2048, 256, 0, stream>>>(x, xb, (size_t)N * 512);
        wt_cvt_kernel<<<(256 * 512 + 255) / 256, 256, 0, stream>>>(W0, Wt0, 512, 256, 256);
        wt_cvt_kernel<<<(256 * 256 + 255) / 256, 256, 0, stream>>>(W1, Wt1, 256, 256, 256);
        wt_cvt_kernel<<<(128 * 256 + 255) / 256, 256, 0, stream>>>(W2, Wt2, 256, 64, 128);

        const int gm = (N + 127) / 128;  // 782
        dim3 g0(gm, 2);
        gemm_mfma_kernel<1, 0><<<g0, 256, 0, stream>>>(xb, Wt0, b0, h1b, nullptr, nullptr, nullptr, N, 512, 256);
        gemm_mfma_kernel<1, 0><<<g0, 256, 0, stream>>>(h1b, Wt1, b1, h2b, nullptr, nullptr, nullptr, N, 256, 256);
        dim3 g2(gm, 1);
        gemm_mfma_kernel<0, 1><<<g2, 256, 0, stream>>>(h2b, Wt2, b2, nullptr, h16, ua, dis, N, 256, 64);
    } else {
        const int Ms = 12500;
        float* hf  = (float*)alloc((size_t)N * 64 * 4);
        float* h1s = (float*)alloc((size_t)Ms * 256 * 4);
        float* h2s = (float*)alloc((size_t)Ms * 256 * 4);
        for (int s0 = 0; s0 < N; s0 += Ms) {
            int rows = (N - s0 < Ms) ? (N - s0) : Ms;
            dim3 g1((rows + 63) / 64, 4);
            gemm_bias_kernel<1><<<g1, 256, 0, stream>>>(x + (size_t)s0 * 512, W0, b0, h1s, rows, 512, 256);
            gemm_bias_kernel<1><<<g1, 256, 0, stream>>>(h1s, W1, b1, h2s, rows, 256, 256);
            dim3 g3((rows + 63) / 64, 1);
            gemm_bias_kernel<0><<<g3, 256, 0, stream>>>(h2s, W2, b2, hf + (size_t)s0 * 64, rows, 256, 64);
        }
        h16u0_kernel<<<(N * 64 + 255) / 256, 256, 0, stream>>>(hf, dis, h16, ua, N * 64);
    }

    // ---- APPNP propagation: 10 plane-chunked steps on u (fp16 planes) ----
    dim3 pgrid(N / 16, 4);   // 6250 x 4, blockIdx.y = chunk
    const _Float16* uin = ua;
    for (int k = 0; k < 10; ++k) {
        if (k == 9) {
            appnp_plane16_kernel<1><<<pgrid, 256, 0, stream>>>(rowptr, srcs, dis, uin, h16, out);
        } else {
            _Float16* uout = (k & 1) ? ua : ub;
            appnp_plane16_kernel<0><<<pgrid, 256, 0, stream>>>(rowptr, srcs, dis, uin, h16, uout);
            uin = uout;
        }
    }
}

// Round 8
// 992.667 us; speedup vs baseline: 2.0029x; 1.1949x over previous
//
#include <hip/hip_runtime.h>
#include <cstdint>
#include <cstddef>

#define NN 100000
#define BSHIFT 9
#define NBUK ((NN + 511) >> 9)   // 196
#define NB_PART 256
#define PART_T 256

typedef __attribute__((ext_vector_type(4))) float f32x4;
typedef __attribute__((ext_vector_type(8))) short bf16x8;
typedef __attribute__((ext_vector_type(8))) _Float16 f16x8;

__device__ __forceinline__ unsigned short f2bf(float x) {
    unsigned int u = __builtin_bit_cast(unsigned int, x);
    unsigned int r = (u + 0x7fffu + ((u >> 16) & 1u)) >> 16;
    return (unsigned short)r;
}

// deg_inv_sqrt with self-loop (+1)
__global__ void dis_kernel(const int* __restrict__ cnt, float* __restrict__ dis, int N) {
    int i = blockIdx.x * blockDim.x + threadIdx.x;
    if (i < N) dis[i] = rsqrtf((float)(cnt[i] + 1));
}

// ---- multi-block exclusive scan over node counts -> rowptr ---------
#define SCAN_B 128
#define SCAN_T 256
#define SCAN_CH 4  // 128*256*4 = 131072 >= NN

__global__ __launch_bounds__(SCAN_T) void scan_part_kernel(const int* __restrict__ cnt,
                                                           int* __restrict__ bsum, int N) {
    __shared__ int s[SCAN_T];
    int b = blockIdx.x, t = threadIdx.x;
    int base = b * SCAN_T * SCAN_CH + t * SCAN_CH;
    int sum = 0;
#pragma unroll
    for (int j = 0; j < SCAN_CH; ++j) {
        int i = base + j;
        if (i < N) sum += cnt[i];
    }
    s[t] = sum;
    __syncthreads();
    for (int off = SCAN_T / 2; off > 0; off >>= 1) {
        if (t < off) s[t] += s[t + off];
        __syncthreads();
    }
    if (t == 0) bsum[b] = s[0];
}

__global__ __launch_bounds__(SCAN_B) void scan_bsum_kernel(const int* __restrict__ bsum,
                                                           int* __restrict__ bofs) {
    __shared__ int s[SCAN_B];
    int t = threadIdx.x;
    int v = bsum[t];
    s[t] = v;
    __syncthreads();
    for (int off = 1; off < SCAN_B; off <<= 1) {
        int x = (t >= off) ? s[t - off] : 0;
        __syncthreads();
        s[t] += x;
        __syncthreads();
    }
    bofs[t] = s[t] - v;  // exclusive
}

__global__ __launch_bounds__(SCAN_T) void scan_write_kernel(const int* __restrict__ cnt,
                                                            const int* __restrict__ bofs,
                                                            int* __restrict__ rowptr,
                                                            int N, int E) {
    __shared__ int s[SCAN_T];
    int b = blockIdx.x, t = threadIdx.x;
    int base = b * SCAN_T * SCAN_CH + t * SCAN_CH;
    int loc[SCAN_CH];
    int sum = 0;
#pragma unroll
    for (int j = 0; j < SCAN_CH; ++j) {
        int i = base + j;
        int c = (i < N) ? cnt[i] : 0;
        loc[j] = c;
        sum += c;
    }
    s[t] = sum;
    __syncthreads();
    for (int off = 1; off < SCAN_T; off <<= 1) {
        int x = (t >= off) ? s[t - off] : 0;
        __syncthreads();
        s[t] += x;
        __syncthreads();
    }
    int run = bofs[b] + s[t] - sum;
#pragma unroll
    for (int j = 0; j < SCAN_CH; ++j) {
        int i = base + j;
        if (i < N) {
            rowptr[i] = run;
            run += loc[j];
        }
    }
    if (b == 0 && t == 0) rowptr[N] = E;
}

// ---- 2-level counting sort (bucket partition, line-dense writes) ----
__global__ __launch_bounds__(PART_T) void part_count_kernel(const int* __restrict__ ecol,
                                                            int* __restrict__ blockcnt, int E) {
    __shared__ int hist[NBUK];
    int b = blockIdx.x, t = threadIdx.x;
    for (int i = t; i < NBUK; i += PART_T) hist[i] = 0;
    __syncthreads();
    int CH = (E + NB_PART - 1) / NB_PART;
    int lo = b * CH;
    int hi = lo + CH; if (hi > E) hi = E;
    for (int e = lo + t; e < hi; e += PART_T)
        atomicAdd(&hist[ecol[e] >> BSHIFT], 1);
    __syncthreads();
    for (int i = t; i < NBUK; i += PART_T) blockcnt[i * NB_PART + b] = hist[i];
}

__global__ __launch_bounds__(NB_PART) void part_scan_kernel(const int* __restrict__ blockcnt,
                                                            int* __restrict__ boffrel,
                                                            int* __restrict__ buktot) {
    __shared__ int s[NB_PART];
    int k = blockIdx.x, t = threadIdx.x;
    int v = blockcnt[k * NB_PART + t];
    s[t] = v;
    __syncthreads();
    for (int off = 1; off < NB_PART; off <<= 1) {
        int x = (t >= off) ? s[t - off] : 0;
        __syncthreads();
        s[t] += x;
        __syncthreads();
    }
    boffrel[k * NB_PART + t] = s[t] - v;  // exclusive, bucket-relative
    if (t == NB_PART - 1) buktot[k] = s[t];
}

__global__ __launch_bounds__(256) void buk_scan_kernel(const int* __restrict__ buktot,
                                                       int* __restrict__ bukbase) {
    __shared__ int s[256];
    int t = threadIdx.x;
    int v = (t < NBUK) ? buktot[t] : 0;
    s[t] = v;
    __syncthreads();
    for (int off = 1; off < 256; off <<= 1) {
        int x = (t >= off) ? s[t - off] : 0;
        __syncthreads();
        s[t] += x;
        __syncthreads();
    }
    if (t < NBUK) bukbase[t] = s[t] - v;  // exclusive
}

__global__ __launch_bounds__(PART_T) void part_write_kernel(const int* __restrict__ erow,
                                                            const int* __restrict__ ecol,
                                                            const int* __restrict__ boffrel,
                                                            const int* __restrict__ bukbase,
                                                            unsigned int* __restrict__ staging, int E) {
    __shared__ int lofs[NBUK];
    int b = blockIdx.x, t = threadIdx.x;
    for (int i = t; i < NBUK; i += PART_T) lofs[i] = bukbase[i] + boffrel[i * NB_PART + b];
    __syncthreads();
    int CH = (E + NB_PART - 1) / NB_PART;
    int lo = b * CH;
    int hi = lo + CH; if (hi > E) hi = E;
    for (int e = lo + t; e < hi; e += PART_T) {
        int c = ecol[e], r = erow[e];
        int k = c >> BSHIFT;
        int pos = atomicAdd(&lofs[k], 1);
        staging[pos] = (unsigned)r | ((unsigned)(c & 511) << 20);
    }
}

__global__ __launch_bounds__(512) void buk_nodecount_kernel(const unsigned int* __restrict__ staging,
                                                            const int* __restrict__ bukbase,
                                                            const int* __restrict__ buktot,
                                                            int* __restrict__ cnt, int N) {
    __shared__ int hist[512];
    int k = blockIdx.x, t = threadIdx.x;
    hist[t] = 0;
    __syncthreads();
    int lo = bukbase[k];
    int hi = lo + buktot[k];
    for (int e = lo + t; e < hi; e += 512)
        atomicAdd(&hist[staging[e] >> 20], 1);
    __syncthreads();
    int node = (k << BSHIFT) + t;
    if (node < N) cnt[node] = hist[t];
}

__global__ __launch_bounds__(512) void part_scatter_kernel(const unsigned int* __restrict__ staging,
                                                           const int* __restrict__ rowptr,
                                                           int* __restrict__ srcs, int N, int E) {
    __shared__ int lnxt[512];
    int k = blockIdx.x, t = threadIdx.x;
    int base = k << BSHIFT;
    int node = base + t;
    lnxt[t] = (node < N) ? rowptr[node] : 0;
    __syncthreads();
    int estart = rowptr[base];
    int hiidx = base + 512; if (hiidx > N) hiidx = N;
    int eend = rowptr[hiidx];
    for (int e = estart + t; e < eend; e += 512) {
        unsigned v = staging[e];
        int p = atomicAdd(&lnxt[v >> 20], 1);
        srcs[p] = (int)(v & 0xFFFFFu);
    }
}

// ------------------------------------------------------------------
// bf16 conversion (n must be a multiple of 8)
__global__ void cvt_bf16_kernel(const float* __restrict__ in, unsigned short* __restrict__ out,
                                size_t n) {
    size_t i = ((size_t)blockIdx.x * blockDim.x + threadIdx.x) * 8;
    size_t stride = (size_t)gridDim.x * blockDim.x * 8;
    for (; i < n; i += stride) {
        float4 a = *(const float4*)(in + i);
        float4 b = *(const float4*)(in + i + 4);
        union { unsigned short u[8]; uint4 v; } r;
        r.u[0] = f2bf(a.x); r.u[1] = f2bf(a.y); r.u[2] = f2bf(a.z); r.u[3] = f2bf(a.w);
        r.u[4] = f2bf(b.x); r.u[5] = f2bf(b.y); r.u[6] = f2bf(b.z); r.u[7] = f2bf(b.w);
        *(uint4*)(out + i) = r.v;
    }
}

// W [K][N] f32 -> Wt [Npad][K] bf16 (transpose + convert, zero-pad rows)
__global__ void wt_cvt_kernel(const float* __restrict__ W, unsigned short* __restrict__ Wt,
                              int K, int N, int Npad) {
    int idx = blockIdx.x * blockDim.x + threadIdx.x;
    int total = Npad * K;
    if (idx >= total) return;
    int n = idx / K, k = idx - n * K;
    float v = (n < N) ? W[(size_t)k * N + n] : 0.f;
    Wt[idx] = f2bf(v);
}

// ------------------------------------------------------------------
// bf16 MFMA GEMM: C = act(A[M,K] @ Bt[N,K]^T + bias)
// FINAL=0: store bf16 C (ldc=N). FINAL=1: store fp16 h16 and u16=dis*h (ldc=64,
// interleaved [M][64]).
template <int RELU, int FINAL>
__global__ __launch_bounds__(256) void gemm_mfma_kernel(
    const unsigned short* __restrict__ A, const unsigned short* __restrict__ Bt,
    const float* __restrict__ bias, unsigned short* __restrict__ Cb,
    _Float16* __restrict__ h16out, _Float16* __restrict__ u16out, const float* __restrict__ dis,
    int M, int K, int N) {
    __shared__ unsigned short sA[128 * 64];
    __shared__ unsigned short sB[128 * 64];
    const int t = threadIdx.x;
    const int wid = t >> 6, lane = t & 63;
    const int bm = blockIdx.x * 128, bn = blockIdx.y * 128;
    const int wr = wid >> 1, wc = wid & 1;

    const int srow = lane >> 3;        // 0..7 row within 8-row group
    const int skb = (lane & 7) * 8;    // bf16-element offset within row (16B granules)

    f32x4 acc[4][4] = {};

    for (int k0 = 0; k0 < K; k0 += 64) {
#pragma unroll
        for (int j = 0; j < 4; ++j) {
            int rbase = (wid * 4 + j) * 8;
            int grow = bm + rbase + srow;
            if (grow >= M) grow = M - 1;
            const unsigned short* asrc = A + (size_t)grow * K + k0 + skb;
            __builtin_amdgcn_global_load_lds(
                (const __attribute__((address_space(1))) unsigned int*)asrc,
                (__attribute__((address_space(3))) unsigned int*)&sA[rbase * 64], 16, 0, 0);
            int gcol = bn + rbase + srow;  // Bt rows are output columns (allocated/padded)
            const unsigned short* bsrc = Bt + (size_t)gcol * K + k0 + skb;
            __builtin_amdgcn_global_load_lds(
                (const __attribute__((address_space(1))) unsigned int*)bsrc,
                (__attribute__((address_space(3))) unsigned int*)&sB[rbase * 64], 16, 0, 0);
        }
        __syncthreads();

        const int fr = lane & 15;
        const int fk = (lane >> 4) * 8;
#pragma unroll
        for (int ks = 0; ks < 2; ++ks) {
            bf16x8 af[4], bfr[4];
#pragma unroll
            for (int m = 0; m < 4; ++m)
                af[m] = *(const bf16x8*)&sA[(wr * 64 + m * 16 + fr) * 64 + ks * 32 + fk];
#pragma unroll
            for (int n = 0; n < 4; ++n)
                bfr[n] = *(const bf16x8*)&sB[(wc * 64 + n * 16 + fr) * 64 + ks * 32 + fk];
#pragma unroll
            for (int m = 0; m < 4; ++m)
#pragma unroll
                for (int n = 0; n < 4; ++n)
                    acc[m][n] = __builtin_amdgcn_mfma_f32_16x16x32_bf16(af[m], bfr[n], acc[m][n], 0, 0, 0);
        }
        __syncthreads();
    }

    const int fr = lane & 15, fq = (lane >> 4) * 4;
#pragma unroll
    for (int m = 0; m < 4; ++m) {
#pragma unroll
        for (int n = 0; n < 4; ++n) {
            int col = bn + wc * 64 + n * 16 + fr;
            if (col >= N) continue;
            float bv = bias[col];
#pragma unroll
            for (int q = 0; q < 4; ++q) {
                int r = bm + wr * 64 + m * 16 + fq + q;
                if (r >= M) continue;
                float v = acc[m][n][q] + bv;
                if (RELU) v = fmaxf(v, 0.f);
                if (!FINAL) {
                    Cb[(size_t)r * N + col] = f2bf(v);
                } else {
                    h16out[(size_t)r * 64 + col] = (_Float16)v;
                    u16out[(size_t)r * 64 + col] = (_Float16)(dis[r] * v);
                }
            }
        }
    }
}

// ------------------------------------------------------------------
// fp32 fallback GEMM (proven): C = act(A@B + bias)
template <int RELU>
__global__ __launch_bounds__(256) void gemm_bias_kernel(
    const float* __restrict__ A, const float* __restrict__ B,
    const float* __restrict__ bias, float* __restrict__ C,
    int M, int K, int N) {
    __shared__ float sA[16][64];
    __shared__ float sB[16][64];
    const int bm = blockIdx.x * 64;
    const int bn = blockIdx.y * 64;
    const int t = threadIdx.x;
    const int tx = t & 15, ty = t >> 4;
    const int arow_l = t >> 2;
    const int akk = (t & 3) * 4;
    const int brow = t >> 4;
    const int bcol = (t & 15) * 4;
    float acc[4][4] = {};

    for (int k0 = 0; k0 < K; k0 += 16) {
        float4 av = make_float4(0.f, 0.f, 0.f, 0.f);
        int arow = bm + arow_l;
        if (arow < M) av = *(const float4*)(A + (size_t)arow * K + k0 + akk);
        float4 bv = *(const float4*)(B + (size_t)(k0 + brow) * N + bn + bcol);
        sA[akk + 0][arow_l] = av.x;
        sA[akk + 1][arow_l] = av.y;
        sA[akk + 2][arow_l] = av.z;
        sA[akk + 3][arow_l] = av.w;
        *(float4*)&sB[brow][bcol] = bv;
        __syncthreads();
#pragma unroll
        for (int k = 0; k < 16; ++k) {
            float4 a4 = *(const float4*)&sA[k][ty * 4];
            float4 b4 = *(const float4*)&sB[k][tx * 4];
            acc[0][0] += a4.x * b4.x; acc[0][1] += a4.x * b4.y; acc[0][2] += a4.x * b4.z; acc[0][3] += a4.x * b4.w;
            acc[1][0] += a4.y * b4.x; acc[1][1] += a4.y * b4.y; acc[1][2] += a4.y * b4.z; acc[1][3] += a4.y * b4.w;
            acc[2][0] += a4.z * b4.x; acc[2][1] += a4.z * b4.y; acc[2][2] += a4.z * b4.z; acc[2][3] += a4.z * b4.w;
            acc[3][0] += a4.w * b4.x; acc[3][1] += a4.w * b4.y; acc[3][2] += a4.w * b4.z; acc[3][3] += a4.w * b4.w;
        }
        __syncthreads();
    }

#pragma unroll
    for (int i = 0; i < 4; ++i) {
        int row = bm + ty * 4 + i;
        if (row >= M) continue;
#pragma unroll
        for (int j = 0; j < 4; ++j) {
            int colg = bn + tx * 4 + j;
            float v = acc[i][j] + bias[colg];
            if (RELU) v = fmaxf(v, 0.f);
            C[(size_t)row * N + colg] = v;
        }
    }
}

// fallback: h fp32 -> h16, u16 = dis*h (interleaved)
__global__ void h16u0_kernel(const float* __restrict__ h, const float* __restrict__ dis,
                             _Float16* __restrict__ h16, _Float16* __restrict__ u16, int total) {
    int i = blockIdx.x * blockDim.x + threadIdx.x;
    if (i < total) {
        float v = h[i];
        h16[i] = (_Float16)v;
        u16[i] = (_Float16)(dis[i >> 6] * v);
    }
}

// ------------------------------------------------------------------
// APPNP step on u = dis*z (fp16 state, PACKED fp16 accumulate):
//   S = sum_e u[src];  z' = 0.8*d*(S + u[n]) + 0.2*h
// FINAL=0 stores u' = d*z' (fp16); FINAL=1 stores z' (fp32 out).
// Wave layout: 8 edge-groups x 8 feature-lanes (8 halves = 16B per lane).
// Inner loop uses v_pk_add_f16 (4 packed adds per 16B) instead of 8 cvt + 8 add;
// the 8-group shuffle reduce is also packed. Epilogue converts once to fp32
// (d and the 0.8/0.2 blend stay fp32 to avoid systematic drift).
template <int FINAL>
__global__ __launch_bounds__(256) void appnp_step16_kernel(
    const int* __restrict__ rowptr, const int* __restrict__ srcs,
    const float* __restrict__ dis, const _Float16* __restrict__ uin,
    const _Float16* __restrict__ hbuf, void* __restrict__ outbuf, int N) {
    int node = blockIdx.x * 4 + (threadIdx.x >> 6);
    if (node >= N) return;
    int lane = threadIdx.x & 63;
    int eg = lane >> 3;   // edge group 0..7
    int fl = lane & 7;    // 8-half chunk index (64 feats)

    int start = rowptr[node];
    int end = rowptr[node + 1];
    f16x8 acc = {};
    for (int e = start + eg; e < end; e += 8) {
        int s = srcs[e];
        f16x8 zv = *(const f16x8*)(uin + (size_t)s * 64 + fl * 8);
        acc += zv;   // 4x v_pk_add_f16
    }
    // packed reduce across the 8 edge groups
    union { f16x8 h; unsigned int w[4]; } uacc, uoth;
    uacc.h = acc;
#pragma unroll
    for (int m = 8; m <= 32; m <<= 1) {
#pragma unroll
        for (int j = 0; j < 4; ++j) uoth.w[j] = __shfl_xor(uacc.w[j], m);
        uacc.h += uoth.h;
    }

    if (eg == 0) {
        float d = dis[node];
        f16x8 us = *(const f16x8*)(uin + (size_t)node * 64 + fl * 8);
        f16x8 hv = *(const f16x8*)(hbuf + (size_t)node * 64 + fl * 8);
        float o[8];
#pragma unroll
        for (int j = 0; j < 8; ++j)
            o[j] = 0.8f * d * ((float)uacc.h[j] + (float)us[j]) + 0.2f * (float)hv[j];
        if (FINAL) {
            float* op = (float*)outbuf + (size_t)node * 64 + fl * 8;
            *(float4*)op = make_float4(o[0], o[1], o[2], o[3]);
            *(float4*)(op + 4) = make_float4(o[4], o[5], o[6], o[7]);
        } else {
            f16x8 ov;
#pragma unroll
            for (int j = 0; j < 8; ++j) ov[j] = (_Float16)(d * o[j]);
            *(f16x8*)((_Float16*)outbuf + (size_t)node * 64 + fl * 8) = ov;
        }
    }
}

// ------------------------------------------------------------------
extern "C" void kernel_launch(void* const* d_in, const int* in_sizes, int n_in,
                              void* d_out, int out_size, void* d_ws, size_t ws_size,
                              hipStream_t stream) {
    const float* x  = (const float*)d_in[0];
    const int*   ei = (const int*)d_in[1];
    const float* W0 = (const float*)d_in[2];
    const float* b0 = (const float*)d_in[3];
    const float* W1 = (const float*)d_in[4];
    const float* b1 = (const float*)d_in[5];
    const float* W2 = (const float*)d_in[6];
    const float* b2 = (const float*)d_in[7];
    float* out = (float*)d_out;

    const int N = NN;
    const int E = in_sizes[1] / 2;
    const int* erow = ei;       // sources
    const int* ecol = ei + E;   // targets
    (void)out_size; (void)n_in;

    char* ws = (char*)d_ws;
    size_t off = 0;
    auto alloc = [&](size_t bytes) -> void* {
        void* p = ws + off;
        off += (bytes + 255) & ~(size_t)255;
        return p;
    };
    // common
    int*   cnt      = (int*)alloc((size_t)N * 4);
    int*   rowptr   = (int*)alloc((size_t)(N + 1) * 4);
    float* dis      = (float*)alloc((size_t)N * 4);
    int*   bsum     = (int*)alloc((size_t)SCAN_B * 4);
    int*   bofs     = (int*)alloc((size_t)SCAN_B * 4);
    int*   blockcnt = (int*)alloc((size_t)NBUK * NB_PART * 4);
    int*   boffrel  = (int*)alloc((size_t)NBUK * NB_PART * 4);
    int*   buktot   = (int*)alloc((size_t)NBUK * 4);
    int*   bukbase  = (int*)alloc((size_t)NBUK * 4);
    unsigned int* staging = (unsigned int*)alloc((size_t)E * 4);
    int*   srcs     = (int*)alloc((size_t)E * 4);
    _Float16* h16 = (_Float16*)alloc((size_t)N * 64 * 2);
    _Float16* ua  = (_Float16*)alloc((size_t)N * 64 * 2);
    _Float16* ub  = (_Float16*)alloc((size_t)N * 64 * 2);
    size_t common_end = off;

    // bf16-path extra
    size_t need_bf16 = common_end
        + (((size_t)N * 512 * 2 + 255) & ~(size_t)255)     // xb
        + ((256 * 512 * 2 + 255) & ~(size_t)255)           // Wt0
        + ((256 * 256 * 2 + 255) & ~(size_t)255)           // Wt1
        + ((128 * 256 * 2 + 255) & ~(size_t)255)           // Wt2 (padded)
        + (((size_t)N * 256 * 2 + 255) & ~(size_t)255)     // h1b
        + (((size_t)N * 256 * 2 + 255) & ~(size_t)255);    // h2b
    const bool use_bf16 = (ws_size >= need_bf16 + (1u << 20));

    // ---- 2-level counting sort into CSC (no global atomics on hot paths) ----
    part_count_kernel<<<NB_PART, PART_T, 0, stream>>>(ecol, blockcnt, E);
    part_scan_kernel<<<NBUK, NB_PART, 0, stream>>>(blockcnt, boffrel, buktot);
    buk_scan_kernel<<<1, 256, 0, stream>>>(buktot, bukbase);
    part_write_kernel<<<NB_PART, PART_T, 0, stream>>>(erow, ecol, boffrel, bukbase, staging, E);
    buk_nodecount_kernel<<<NBUK, 512, 0, stream>>>(staging, bukbase, buktot, cnt, N);
    dis_kernel<<<(N + 255) / 256, 256, 0, stream>>>(cnt, dis, N);
    scan_part_kernel<<<SCAN_B, SCAN_T, 0, stream>>>(cnt, bsum, N);
    scan_bsum_kernel<<<1, SCAN_B, 0, stream>>>(bsum, bofs);
    scan_write_kernel<<<SCAN_B, SCAN_T, 0, stream>>>(cnt, bofs, rowptr, N, E);
    part_scatter_kernel<<<NBUK, 512, 0, stream>>>(staging, rowptr, srcs, N, E);

    // ---- MLP -> h16 (fp16) and ua = u0 = dis*h (fp16) ----
    if (use_bf16) {
        unsigned short* xb  = (unsigned short*)alloc((size_t)N * 512 * 2);
        unsigned short* Wt0 = (unsigned short*)alloc(256 * 512 * 2);
        unsigned short* Wt1 = (unsigned short*)alloc(256 * 256 * 2);
        unsigned short* Wt2 = (unsigned short*)alloc(128 * 256 * 2);
        unsigned short* h1b = (unsigned short*)alloc((size_t)N * 256 * 2);
        unsigned short* h2b = (unsigned short*)alloc((size_t)N * 256 * 2);

        cvt_bf16_kernel<<<2048, 256, 0, stream>>>(x, xb, (size_t)N * 512);
        wt_cvt_kernel<<<(256 * 512 + 255) / 256, 256, 0, stream>>>(W0, Wt0, 512, 256, 256);
        wt_cvt_kernel<<<(256 * 256 + 255) / 256, 256, 0, stream>>>(W1, Wt1, 256, 256, 256);
        wt_cvt_kernel<<<(128 * 256 + 255) / 256, 256, 0, stream>>>(W2, Wt2, 256, 64, 128);

        const int gm = (N + 127) / 128;  // 782
        dim3 g0(gm, 2);
        gemm_mfma_kernel<1, 0><<<g0, 256, 0, stream>>>(xb, Wt0, b0, h1b, nullptr, nullptr, nullptr, N, 512, 256);
        gemm_mfma_kernel<1, 0><<<g0, 256, 0, stream>>>(h1b, Wt1, b1, h2b, nullptr, nullptr, nullptr, N, 256, 256);
        dim3 g2(gm, 1);
        gemm_mfma_kernel<0, 1><<<g2, 256, 0, stream>>>(h2b, Wt2, b2, nullptr, h16, ua, dis, N, 256, 64);
    } else {
        const int Ms = 12500;
        float* hf  = (float*)alloc((size_t)N * 64 * 4);
        float* h1s = (float*)alloc((size_t)Ms * 256 * 4);
        float* h2s = (float*)alloc((size_t)Ms * 256 * 4);
        for (int s0 = 0; s0 < N; s0 += Ms) {
            int rows = (N - s0 < Ms) ? (N - s0) : Ms;
            dim3 g1((rows + 63) / 64, 4);
            gemm_bias_kernel<1><<<g1, 256, 0, stream>>>(x + (size_t)s0 * 512, W0, b0, h1s, rows, 512, 256);
            gemm_bias_kernel<1><<<g1, 256, 0, stream>>>(h1s, W1, b1, h2s, rows, 256, 256);
            dim3 g3((rows + 63) / 64, 1);
            gemm_bias_kernel<0><<<g3, 256, 0, stream>>>(h2s, W2, b2, hf + (size_t)s0 * 64, rows, 256, 64);
        }
        h16u0_kernel<<<(N * 64 + 255) / 256, 256, 0, stream>>>(hf, dis, h16, ua, N * 64);
    }

    // ---- APPNP propagation: 10 steps on u (fp16, packed accumulate) ----
    const _Float16* uin = ua;
    for (int k = 0; k < 10; ++k) {
        if (k == 9) {
            appnp_step16_kernel<1><<<(N + 3) / 4, 256, 0, stream>>>(rowptr, srcs, dis, uin, h16, out, N);
        } else {
            _Float16* uout = (k & 1) ? ua : ub;
            appnp_step16_kernel<0><<<(N + 3) / 4, 256, 0, stream>>>(rowptr, srcs, dis, uin, h16, uout, N);
            uin = uout;
        }
    }
}

// Round 9
// 902.358 us; speedup vs baseline: 2.2033x; 1.1001x over previous
//
#include <hip/hip_runtime.h>
#include <cstdint>
#include <cstddef>

#define NN 100000
#define BSHIFT 9
#define NBUK ((NN + 511) >> 9)   // 196
#define NB_PART 256
#define PART_T 256

typedef __attribute__((ext_vector_type(4))) float f32x4;
typedef __attribute__((ext_vector_type(8))) short bf16x8;
typedef __attribute__((ext_vector_type(8))) _Float16 f16x8;

__device__ __forceinline__ unsigned short f2bf(float x) {
    unsigned int u = __builtin_bit_cast(unsigned int, x);
    unsigned int r = (u + 0x7fffu + ((u >> 16) & 1u)) >> 16;
    return (unsigned short)r;
}

// deg_inv_sqrt with self-loop (+1)
__global__ void dis_kernel(const int* __restrict__ cnt, float* __restrict__ dis, int N) {
    int i = blockIdx.x * blockDim.x + threadIdx.x;
    if (i < N) dis[i] = rsqrtf((float)(cnt[i] + 1));
}

// ---- multi-block exclusive scan over node counts -> rowptr ---------
#define SCAN_B 128
#define SCAN_T 256
#define SCAN_CH 4  // 128*256*4 = 131072 >= NN

__global__ __launch_bounds__(SCAN_T) void scan_part_kernel(const int* __restrict__ cnt,
                                                           int* __restrict__ bsum, int N) {
    __shared__ int s[SCAN_T];
    int b = blockIdx.x, t = threadIdx.x;
    int base = b * SCAN_T * SCAN_CH + t * SCAN_CH;
    int sum = 0;
#pragma unroll
    for (int j = 0; j < SCAN_CH; ++j) {
        int i = base + j;
        if (i < N) sum += cnt[i];
    }
    s[t] = sum;
    __syncthreads();
    for (int off = SCAN_T / 2; off > 0; off >>= 1) {
        if (t < off) s[t] += s[t + off];
        __syncthreads();
    }
    if (t == 0) bsum[b] = s[0];
}

__global__ __launch_bounds__(SCAN_B) void scan_bsum_kernel(const int* __restrict__ bsum,
                                                           int* __restrict__ bofs) {
    __shared__ int s[SCAN_B];
    int t = threadIdx.x;
    int v = bsum[t];
    s[t] = v;
    __syncthreads();
    for (int off = 1; off < SCAN_B; off <<= 1) {
        int x = (t >= off) ? s[t - off] : 0;
        __syncthreads();
        s[t] += x;
        __syncthreads();
    }
    bofs[t] = s[t] - v;  // exclusive
}

__global__ __launch_bounds__(SCAN_T) void scan_write_kernel(const int* __restrict__ cnt,
                                                            const int* __restrict__ bofs,
                                                            int* __restrict__ rowptr,
                                                            int N, int E) {
    __shared__ int s[SCAN_T];
    int b = blockIdx.x, t = threadIdx.x;
    int base = b * SCAN_T * SCAN_CH + t * SCAN_CH;
    int loc[SCAN_CH];
    int sum = 0;
#pragma unroll
    for (int j = 0; j < SCAN_CH; ++j) {
        int i = base + j;
        int c = (i < N) ? cnt[i] : 0;
        loc[j] = c;
        sum += c;
    }
    s[t] = sum;
    __syncthreads();
    for (int off = 1; off < SCAN_T; off <<= 1) {
        int x = (t >= off) ? s[t - off] : 0;
        __syncthreads();
        s[t] += x;
        __syncthreads();
    }
    int run = bofs[b] + s[t] - sum;
#pragma unroll
    for (int j = 0; j < SCAN_CH; ++j) {
        int i = base + j;
        if (i < N) {
            rowptr[i] = run;
            run += loc[j];
        }
    }
    if (b == 0 && t == 0) rowptr[N] = E;
}

// ---- 2-level counting sort (bucket partition, line-dense writes) ----
__global__ __launch_bounds__(PART_T) void part_count_kernel(const int* __restrict__ ecol,
                                                            int* __restrict__ blockcnt, int E) {
    __shared__ int hist[NBUK];
    int b = blockIdx.x, t = threadIdx.x;
    for (int i = t; i < NBUK; i += PART_T) hist[i] = 0;
    __syncthreads();
    int CH = (E + NB_PART - 1) / NB_PART;
    int lo = b * CH;
    int hi = lo + CH; if (hi > E) hi = E;
    for (int e = lo + t; e < hi; e += PART_T)
        atomicAdd(&hist[ecol[e] >> BSHIFT], 1);
    __syncthreads();
    for (int i = t; i < NBUK; i += PART_T) blockcnt[i * NB_PART + b] = hist[i];
}

__global__ __launch_bounds__(NB_PART) void part_scan_kernel(const int* __restrict__ blockcnt,
                                                            int* __restrict__ boffrel,
                                                            int* __restrict__ buktot) {
    __shared__ int s[NB_PART];
    int k = blockIdx.x, t = threadIdx.x;
    int v = blockcnt[k * NB_PART + t];
    s[t] = v;
    __syncthreads();
    for (int off = 1; off < NB_PART; off <<= 1) {
        int x = (t >= off) ? s[t - off] : 0;
        __syncthreads();
        s[t] += x;
        __syncthreads();
    }
    boffrel[k * NB_PART + t] = s[t] - v;  // exclusive, bucket-relative
    if (t == NB_PART - 1) buktot[k] = s[t];
}

__global__ __launch_bounds__(256) void buk_scan_kernel(const int* __restrict__ buktot,
                                                       int* __restrict__ bukbase) {
    __shared__ int s[256];
    int t = threadIdx.x;
    int v = (t < NBUK) ? buktot[t] : 0;
    s[t] = v;
    __syncthreads();
    for (int off = 1; off < 256; off <<= 1) {
        int x = (t >= off) ? s[t - off] : 0;
        __syncthreads();
        s[t] += x;
        __syncthreads();
    }
    if (t < NBUK) bukbase[t] = s[t] - v;  // exclusive
}

__global__ __launch_bounds__(PART_T) void part_write_kernel(const int* __restrict__ erow,
                                                            const int* __restrict__ ecol,
                                                            const int* __restrict__ boffrel,
                                                            const int* __restrict__ bukbase,
                                                            unsigned int* __restrict__ staging, int E) {
    __shared__ int lofs[NBUK];
    int b = blockIdx.x, t = threadIdx.x;
    for (int i = t; i < NBUK; i += PART_T) lofs[i] = bukbase[i] + boffrel[i * NB_PART + b];
    __syncthreads();
    int CH = (E + NB_PART - 1) / NB_PART;
    int lo = b * CH;
    int hi = lo + CH; if (hi > E) hi = E;
    for (int e = lo + t; e < hi; e += PART_T) {
        int c = ecol[e], r = erow[e];
        int k = c >> BSHIFT;
        int pos = atomicAdd(&lofs[k], 1);
        staging[pos] = (unsigned)r | ((unsigned)(c & 511) << 20);
    }
}

__global__ __launch_bounds__(512) void buk_nodecount_kernel(const unsigned int* __restrict__ staging,
                                                            const int* __restrict__ bukbase,
                                                            const int* __restrict__ buktot,
                                                            int* __restrict__ cnt, int N) {
    __shared__ int hist[512];
    int k = blockIdx.x, t = threadIdx.x;
    hist[t] = 0;
    __syncthreads();
    int lo = bukbase[k];
    int hi = lo + buktot[k];
    for (int e = lo + t; e < hi; e += 512)
        atomicAdd(&hist[staging[e] >> 20], 1);
    __syncthreads();
    int node = (k << BSHIFT) + t;
    if (node < N) cnt[node] = hist[t];
}

__global__ __launch_bounds__(512) void part_scatter_kernel(const unsigned int* __restrict__ staging,
                                                           const int* __restrict__ rowptr,
                                                           int* __restrict__ srcs, int N, int E) {
    __shared__ int lnxt[512];
    int k = blockIdx.x, t = threadIdx.x;
    int base = k << BSHIFT;
    int node = base + t;
    lnxt[t] = (node < N) ? rowptr[node] : 0;
    __syncthreads();
    int estart = rowptr[base];
    int hiidx = base + 512; if (hiidx > N) hiidx = N;
    int eend = rowptr[hiidx];
    for (int e = estart + t; e < eend; e += 512) {
        unsigned v = staging[e];
        int p = atomicAdd(&lnxt[v >> 20], 1);
        srcs[p] = (int)(v & 0xFFFFFu);
    }
}

// ------------------------------------------------------------------
// bf16 conversion (n must be a multiple of 8)
__global__ void cvt_bf16_kernel(const float* __restrict__ in, unsigned short* __restrict__ out,
                                size_t n) {
    size_t i = ((size_t)blockIdx.x * blockDim.x + threadIdx.x) * 8;
    size_t stride = (size_t)gridDim.x * blockDim.x * 8;
    for (; i < n; i += stride) {
        float4 a = *(const float4*)(in + i);
        float4 b = *(const float4*)(in + i + 4);
        union { unsigned short u[8]; uint4 v; } r;
        r.u[0] = f2bf(a.x); r.u[1] = f2bf(a.y); r.u[2] = f2bf(a.z); r.u[3] = f2bf(a.w);
        r.u[4] = f2bf(b.x); r.u[5] = f2bf(b.y); r.u[6] = f2bf(b.z); r.u[7] = f2bf(b.w);
        *(uint4*)(out + i) = r.v;
    }
}

// W [K][N] f32 -> Wt [Npad][K] bf16 (transpose + convert, zero-pad rows)
__global__ void wt_cvt_kernel(const float* __restrict__ W, unsigned short* __restrict__ Wt,
                              int K, int N, int Npad) {
    int idx = blockIdx.x * blockDim.x + threadIdx.x;
    int total = Npad * K;
    if (idx >= total) return;
    int n = idx / K, k = idx - n * K;
    float v = (n < N) ? W[(size_t)k * N + n] : 0.f;
    Wt[idx] = f2bf(v);
}

// ------------------------------------------------------------------
// bf16 MFMA GEMM: C = act(A[M,K] @ Bt[N,K]^T + bias)
// FINAL=0: store bf16 C (ldc=N). FINAL=1: store fp16 h16 and u16=dis*h (ldc=64).
template <int RELU, int FINAL>
__global__ __launch_bounds__(256) void gemm_mfma_kernel(
    const unsigned short* __restrict__ A, const unsigned short* __restrict__ Bt,
    const float* __restrict__ bias, unsigned short* __restrict__ Cb,
    _Float16* __restrict__ h16out, _Float16* __restrict__ u16out, const float* __restrict__ dis,
    int M, int K, int N) {
    __shared__ unsigned short sA[128 * 64];
    __shared__ unsigned short sB[128 * 64];
    const int t = threadIdx.x;
    const int wid = t >> 6, lane = t & 63;
    const int bm = blockIdx.x * 128, bn = blockIdx.y * 128;
    const int wr = wid >> 1, wc = wid & 1;

    const int srow = lane >> 3;        // 0..7 row within 8-row group
    const int skb = (lane & 7) * 8;    // bf16-element offset within row (16B granules)

    f32x4 acc[4][4] = {};

    for (int k0 = 0; k0 < K; k0 += 64) {
#pragma unroll
        for (int j = 0; j < 4; ++j) {
            int rbase = (wid * 4 + j) * 8;
            int grow = bm + rbase + srow;
            if (grow >= M) grow = M - 1;
            const unsigned short* asrc = A + (size_t)grow * K + k0 + skb;
            __builtin_amdgcn_global_load_lds(
                (const __attribute__((address_space(1))) unsigned int*)asrc,
                (__attribute__((address_space(3))) unsigned int*)&sA[rbase * 64], 16, 0, 0);
            int gcol = bn + rbase + srow;  // Bt rows are output columns (allocated/padded)
            const unsigned short* bsrc = Bt + (size_t)gcol * K + k0 + skb;
            __builtin_amdgcn_global_load_lds(
                (const __attribute__((address_space(1))) unsigned int*)bsrc,
                (__attribute__((address_space(3))) unsigned int*)&sB[rbase * 64], 16, 0, 0);
        }
        __syncthreads();

        const int fr = lane & 15;
        const int fk = (lane >> 4) * 8;
#pragma unroll
        for (int ks = 0; ks < 2; ++ks) {
            bf16x8 af[4], bfr[4];
#pragma unroll
            for (int m = 0; m < 4; ++m)
                af[m] = *(const bf16x8*)&sA[(wr * 64 + m * 16 + fr) * 64 + ks * 32 + fk];
#pragma unroll
            for (int n = 0; n < 4; ++n)
                bfr[n] = *(const bf16x8*)&sB[(wc * 64 + n * 16 + fr) * 64 + ks * 32 + fk];
#pragma unroll
            for (int m = 0; m < 4; ++m)
#pragma unroll
                for (int n = 0; n < 4; ++n)
                    acc[m][n] = __builtin_amdgcn_mfma_f32_16x16x32_bf16(af[m], bfr[n], acc[m][n], 0, 0, 0);
        }
        __syncthreads();
    }

    const int fr = lane & 15, fq = (lane >> 4) * 4;
#pragma unroll
    for (int m = 0; m < 4; ++m) {
#pragma unroll
        for (int n = 0; n < 4; ++n) {
            int col = bn + wc * 64 + n * 16 + fr;
            if (col >= N) continue;
            float bv = bias[col];
#pragma unroll
            for (int q = 0; q < 4; ++q) {
                int r = bm + wr * 64 + m * 16 + fq + q;
                if (r >= M) continue;
                float v = acc[m][n][q] + bv;
                if (RELU) v = fmaxf(v, 0.f);
                if (!FINAL) {
                    Cb[(size_t)r * N + col] = f2bf(v);
                } else {
                    h16out[(size_t)r * 64 + col] = (_Float16)v;
                    u16out[(size_t)r * 64 + col] = (_Float16)(dis[r] * v);
                }
            }
        }
    }
}

// ------------------------------------------------------------------
// fp32 fallback GEMM (proven): C = act(A@B + bias)
template <int RELU>
__global__ __launch_bounds__(256) void gemm_bias_kernel(
    const float* __restrict__ A, const float* __restrict__ B,
    const float* __restrict__ bias, float* __restrict__ C,
    int M, int K, int N) {
    __shared__ float sA[16][64];
    __shared__ float sB[16][64];
    const int bm = blockIdx.x * 64;
    const int bn = blockIdx.y * 64;
    const int t = threadIdx.x;
    const int tx = t & 15, ty = t >> 4;
    const int arow_l = t >> 2;
    const int akk = (t & 3) * 4;
    const int brow = t >> 4;
    const int bcol = (t & 15) * 4;
    float acc[4][4] = {};

    for (int k0 = 0; k0 < K; k0 += 16) {
        float4 av = make_float4(0.f, 0.f, 0.f, 0.f);
        int arow = bm + arow_l;
        if (arow < M) av = *(const float4*)(A + (size_t)arow * K + k0 + akk);
        float4 bv = *(const float4*)(B + (size_t)(k0 + brow) * N + bn + bcol);
        sA[akk + 0][arow_l] = av.x;
        sA[akk + 1][arow_l] = av.y;
        sA[akk + 2][arow_l] = av.z;
        sA[akk + 3][arow_l] = av.w;
        *(float4*)&sB[brow][bcol] = bv;
        __syncthreads();
#pragma unroll
        for (int k = 0; k < 16; ++k) {
            float4 a4 = *(const float4*)&sA[k][ty * 4];
            float4 b4 = *(const float4*)&sB[k][tx * 4];
            acc[0][0] += a4.x * b4.x; acc[0][1] += a4.x * b4.y; acc[0][2] += a4.x * b4.z; acc[0][3] += a4.x * b4.w;
            acc[1][0] += a4.y * b4.x; acc[1][1] += a4.y * b4.y; acc[1][2] += a4.y * b4.z; acc[1][3] += a4.y * b4.w;
            acc[2][0] += a4.z * b4.x; acc[2][1] += a4.z * b4.y; acc[2][2] += a4.z * b4.z; acc[2][3] += a4.z * b4.w;
            acc[3][0] += a4.w * b4.x; acc[3][1] += a4.w * b4.y; acc[3][2] += a4.w * b4.z; acc[3][3] += a4.w * b4.w;
        }
        __syncthreads();
    }

#pragma unroll
    for (int i = 0; i < 4; ++i) {
        int row = bm + ty * 4 + i;
        if (row >= M) continue;
#pragma unroll
        for (int j = 0; j < 4; ++j) {
            int colg = bn + tx * 4 + j;
            float v = acc[i][j] + bias[colg];
            if (RELU) v = fmaxf(v, 0.f);
            C[(size_t)row * N + colg] = v;
        }
    }
}

// fallback: h fp32 -> h16, u16 = dis*h
__global__ void h16u0_kernel(const float* __restrict__ h, const float* __restrict__ dis,
                             _Float16* __restrict__ h16, _Float16* __restrict__ u16, int total) {
    int i = blockIdx.x * blockDim.x + threadIdx.x;
    if (i < total) {
        float v = h[i];
        h16[i] = (_Float16)v;
        u16[i] = (_Float16)(dis[i >> 6] * v);
    }
}

// ------------------------------------------------------------------
// APPNP step on u = dis*z (fp16 state, packed fp16 accumulate, 2x unrolled
// edge loop with dual accumulators -> 2 outstanding gathers per wave):
//   S = sum_e u[src];  z' = 0.8*d*(S + u[n]) + 0.2*h
// FINAL=0 stores u' = d*z' (fp16); FINAL=1 stores z' (fp32 out).
// Wave layout: 8 edge-groups x 8 feature-lanes (16B per lane).
template <int FINAL>
__global__ __launch_bounds__(256) void appnp_step16_kernel(
    const int* __restrict__ rowptr, const int* __restrict__ srcs,
    const float* __restrict__ dis, const _Float16* __restrict__ uin,
    const _Float16* __restrict__ hbuf, void* __restrict__ outbuf, int N) {
    int node = blockIdx.x * 4 + (threadIdx.x >> 6);
    if (node >= N) return;
    int lane = threadIdx.x & 63;
    int eg = lane >> 3;   // edge group 0..7
    int fl = lane & 7;    // 8-half chunk index (64 feats)

    int start = rowptr[node];
    int end = rowptr[node + 1];

    // hoist epilogue operands (latency hides under the edge loop/reduce)
    float d = dis[node];
    f16x8 us = *(const f16x8*)(uin + (size_t)node * 64 + fl * 8);
    f16x8 hv = *(const f16x8*)(hbuf + (size_t)node * 64 + fl * 8);

    f16x8 acc0 = {}, acc1 = {};
    int e = start + eg;
    // unroll x2: both gathers issue before either result is consumed
    for (; e + 8 < end; e += 16) {
        int s0 = srcs[e];
        int s1 = srcs[e + 8];
        f16x8 z0 = *(const f16x8*)(uin + (size_t)s0 * 64 + fl * 8);
        f16x8 z1 = *(const f16x8*)(uin + (size_t)s1 * 64 + fl * 8);
        acc0 += z0;
        acc1 += z1;
    }
    if (e < end) {
        int s0 = srcs[e];
        acc0 += *(const f16x8*)(uin + (size_t)s0 * 64 + fl * 8);
    }
    acc0 += acc1;

    // packed reduce across the 8 edge groups
    union { f16x8 h; unsigned int w[4]; } uacc, uoth;
    uacc.h = acc0;
#pragma unroll
    for (int m = 8; m <= 32; m <<= 1) {
#pragma unroll
        for (int j = 0; j < 4; ++j) uoth.w[j] = __shfl_xor(uacc.w[j], m);
        uacc.h += uoth.h;
    }

    if (eg == 0) {
        float o[8];
#pragma unroll
        for (int j = 0; j < 8; ++j)
            o[j] = 0.8f * d * ((float)uacc.h[j] + (float)us[j]) + 0.2f * (float)hv[j];
        if (FINAL) {
            float* op = (float*)outbuf + (size_t)node * 64 + fl * 8;
            *(float4*)op = make_float4(o[0], o[1], o[2], o[3]);
            *(float4*)(op + 4) = make_float4(o[4], o[5], o[6], o[7]);
        } else {
            f16x8 ov;
#pragma unroll
            for (int j = 0; j < 8; ++j) ov[j] = (_Float16)(d * o[j]);
            *(f16x8*)((_Float16*)outbuf + (size_t)node * 64 + fl * 8) = ov;
        }
    }
}

// ------------------------------------------------------------------
extern "C" void kernel_launch(void* const* d_in, const int* in_sizes, int n_in,
                              void* d_out, int out_size, void* d_ws, size_t ws_size,
                              hipStream_t stream) {
    const float* x  = (const float*)d_in[0];
    const int*   ei = (const int*)d_in[1];
    const float* W0 = (const float*)d_in[2];
    const float* b0 = (const float*)d_in[3];
    const float* W1 = (const float*)d_in[4];
    const float* b1 = (const float*)d_in[5];
    const float* W2 = (const float*)d_in[6];
    const float* b2 = (const float*)d_in[7];
    float* out = (float*)d_out;

    const int N = NN;
    const int E = in_sizes[1] / 2;
    const int* erow = ei;       // sources
    const int* ecol = ei + E;   // targets
    (void)out_size; (void)n_in;

    char* ws = (char*)d_ws;
    size_t off = 0;
    auto alloc = [&](size_t bytes) -> void* {
        void* p = ws + off;
        off += (bytes + 255) & ~(size_t)255;
        return p;
    };
    // common
    int*   cnt      = (int*)alloc((size_t)N * 4);
    int*   rowptr   = (int*)alloc((size_t)(N + 1) * 4);
    float* dis      = (float*)alloc((size_t)N * 4);
    int*   bsum     = (int*)alloc((size_t)SCAN_B * 4);
    int*   bofs     = (int*)alloc((size_t)SCAN_B * 4);
    int*   blockcnt = (int*)alloc((size_t)NBUK * NB_PART * 4);
    int*   boffrel  = (int*)alloc((size_t)NBUK * NB_PART * 4);
    int*   buktot   = (int*)alloc((size_t)NBUK * 4);
    int*   bukbase  = (int*)alloc((size_t)NBUK * 4);
    unsigned int* staging = (unsigned int*)alloc((size_t)E * 4);
    int*   srcs     = (int*)alloc((size_t)E * 4);
    _Float16* h16 = (_Float16*)alloc((size_t)N * 64 * 2);
    _Float16* ua  = (_Float16*)alloc((size_t)N * 64 * 2);
    _Float16* ub  = (_Float16*)alloc((size_t)N * 64 * 2);
    size_t common_end = off;

    // bf16-path extra
    size_t need_bf16 = common_end
        + (((size_t)N * 512 * 2 + 255) & ~(size_t)255)     // xb
        + ((256 * 512 * 2 + 255) & ~(size_t)255)           // Wt0
        + ((256 * 256 * 2 + 255) & ~(size_t)255)           // Wt1
        + ((128 * 256 * 2 + 255) & ~(size_t)255)           // Wt2 (padded)
        + (((size_t)N * 256 * 2 + 255) & ~(size_t)255)     // h1b
        + (((size_t)N * 256 * 2 + 255) & ~(size_t)255);    // h2b
    const bool use_bf16 = (ws_size >= need_bf16 + (1u << 20));

    // ---- 2-level counting sort into CSC (no global atomics on hot paths) ----
    part_count_kernel<<<NB_PART, PART_T, 0, stream>>>(ecol, blockcnt, E);
    part_scan_kernel<<<NBUK, NB_PART, 0, stream>>>(blockcnt, boffrel, buktot);
    buk_scan_kernel<<<1, 256, 0, stream>>>(buktot, bukbase);
    part_write_kernel<<<NB_PART, PART_T, 0, stream>>>(erow, ecol, boffrel, bukbase, staging, E);
    buk_nodecount_kernel<<<NBUK, 512, 0, stream>>>(staging, bukbase, buktot, cnt, N);
    dis_kernel<<<(N + 255) / 256, 256, 0, stream>>>(cnt, dis, N);
    scan_part_kernel<<<SCAN_B, SCAN_T, 0, stream>>>(cnt, bsum, N);
    scan_bsum_kernel<<<1, SCAN_B, 0, stream>>>(bsum, bofs);
    scan_write_kernel<<<SCAN_B, SCAN_T, 0, stream>>>(cnt, bofs, rowptr, N, E);
    part_scatter_kernel<<<NBUK, 512, 0, stream>>>(staging, rowptr, srcs, N, E);

    // ---- MLP -> h16 (fp16) and ua = u0 = dis*h (fp16) ----
    if (use_bf16) {
        unsigned short* xb  = (unsigned short*)alloc((size_t)N * 512 * 2);
        unsigned short* Wt0 = (unsigned short*)alloc(256 * 512 * 2);
        unsigned short* Wt1 = (unsigned short*)alloc(256 * 256 * 2);
        unsigned short* Wt2 = (unsigned short*)alloc(128 * 256 * 2);
        unsigned short* h1b = (unsigned short*)alloc((size_t)N * 256 * 2);
        unsigned short* h2b = (unsigned short*)alloc((size_t)N * 256 * 2);

        cvt_bf16_kernel<<<2048, 256, 0, stream>>>(x, xb, (size_t)N * 512);
        wt_cvt_kernel<<<(256 * 512 + 255) / 256, 256, 0, stream>>>(W0, Wt0, 512, 256, 256);
        wt_cvt_kernel<<<(256 * 256 + 255) / 256, 256, 0, stream>>>(W1, Wt1, 256, 256, 256);
        wt_cvt_kernel<<<(128 * 256 + 255) / 256, 256, 0, stream>>>(W2, Wt2, 256, 64, 128);

        const int gm = (N + 127) / 128;  // 782
        dim3 g0(gm, 2);
        gemm_mfma_kernel<1, 0><<<g0, 256, 0, stream>>>(xb, Wt0, b0, h1b, nullptr, nullptr, nullptr, N, 512, 256);
        gemm_mfma_kernel<1, 0><<<g0, 256, 0, stream>>>(h1b, Wt1, b1, h2b, nullptr, nullptr, nullptr, N, 256, 256);
        dim3 g2(gm, 1);
        gemm_mfma_kernel<0, 1><<<g2, 256, 0, stream>>>(h2b, Wt2, b2, nullptr, h16, ua, dis, N, 256, 64);
    } else {
        const int Ms = 12500;
        float* hf  = (float*)alloc((size_t)N * 64 * 4);
        float* h1s = (float*)alloc((size_t)Ms * 256 * 4);
        float* h2s = (float*)alloc((size_t)Ms * 256 * 4);
        for (int s0 = 0; s0 < N; s0 += Ms) {
            int rows = (N - s0 < Ms) ? (N - s0) : Ms;
            dim3 g1((rows + 63) / 64, 4);
            gemm_bias_kernel<1><<<g1, 256, 0, stream>>>(x + (size_t)s0 * 512, W0, b0, h1s, rows, 512, 256);
            gemm_bias_kernel<1><<<g1, 256, 0, stream>>>(h1s, W1, b1, h2s, rows, 256, 256);
            dim3 g3((rows + 63) / 64, 1);
            gemm_bias_kernel<0><<<g3, 256, 0, stream>>>(h2s, W2, b2, hf + (size_t)s0 * 64, rows, 256, 64);
        }
        h16u0_kernel<<<(N * 64 + 255) / 256, 256, 0, stream>>>(hf, dis, h16, ua, N * 64);
    }

    // ---- APPNP propagation: 10 steps on u (fp16, packed + unrolled) ----
    const _Float16* uin = ua;
    for (int k = 0; k < 10; ++k) {
        if (k == 9) {
            appnp_step16_kernel<1><<<(N + 3) / 4, 256, 0, stream>>>(rowptr, srcs, dis, uin, h16, out, N);
        } else {
            _Float16* uout = (k & 1) ? ua : ub;
            appnp_step16_kernel<0><<<(N + 3) / 4, 256, 0, stream>>>(rowptr, srcs, dis, uin, h16, uout, N);
            uin = uout;
        }
    }
}

// Round 10
// 893.005 us; speedup vs baseline: 2.2264x; 1.0105x over previous
//
#include <hip/hip_runtime.h>
#include <cstdint>
#include <cstddef>

#define NN 100000
#define BSHIFT 9
#define NBUK ((NN + 511) >> 9)   // 196
#define NB_PART 256
#define PART_T 256

typedef __attribute__((ext_vector_type(4))) float f32x4;
typedef __attribute__((ext_vector_type(8))) short bf16x8;
typedef __attribute__((ext_vector_type(8))) _Float16 f16x8;

__device__ __forceinline__ unsigned short f2bf(float x) {
    unsigned int u = __builtin_bit_cast(unsigned int, x);
    unsigned int r = (u + 0x7fffu + ((u >> 16) & 1u)) >> 16;
    return (unsigned short)r;
}

// deg_inv_sqrt with self-loop (+1)
__global__ void dis_kernel(const int* __restrict__ cnt, float* __restrict__ dis, int N) {
    int i = blockIdx.x * blockDim.x + threadIdx.x;
    if (i < N) dis[i] = rsqrtf((float)(cnt[i] + 1));
}

// ---- multi-block exclusive scan over node counts -> rowptr ---------
#define SCAN_B 128
#define SCAN_T 256
#define SCAN_CH 4  // 128*256*4 = 131072 >= NN

__global__ __launch_bounds__(SCAN_T) void scan_part_kernel(const int* __restrict__ cnt,
                                                           int* __restrict__ bsum, int N) {
    __shared__ int s[SCAN_T];
    int b = blockIdx.x, t = threadIdx.x;
    int base = b * SCAN_T * SCAN_CH + t * SCAN_CH;
    int sum = 0;
#pragma unroll
    for (int j = 0; j < SCAN_CH; ++j) {
        int i = base + j;
        if (i < N) sum += cnt[i];
    }
    s[t] = sum;
    __syncthreads();
    for (int off = SCAN_T / 2; off > 0; off >>= 1) {
        if (t < off) s[t] += s[t + off];
        __syncthreads();
    }
    if (t == 0) bsum[b] = s[0];
}

__global__ __launch_bounds__(SCAN_B) void scan_bsum_kernel(const int* __restrict__ bsum,
                                                           int* __restrict__ bofs) {
    __shared__ int s[SCAN_B];
    int t = threadIdx.x;
    int v = bsum[t];
    s[t] = v;
    __syncthreads();
    for (int off = 1; off < SCAN_B; off <<= 1) {
        int x = (t >= off) ? s[t - off] : 0;
        __syncthreads();
        s[t] += x;
        __syncthreads();
    }
    bofs[t] = s[t] - v;  // exclusive
}

__global__ __launch_bounds__(SCAN_T) void scan_write_kernel(const int* __restrict__ cnt,
                                                            const int* __restrict__ bofs,
                                                            int* __restrict__ rowptr,
                                                            int N, int E) {
    __shared__ int s[SCAN_T];
    int b = blockIdx.x, t = threadIdx.x;
    int base = b * SCAN_T * SCAN_CH + t * SCAN_CH;
    int loc[SCAN_CH];
    int sum = 0;
#pragma unroll
    for (int j = 0; j < SCAN_CH; ++j) {
        int i = base + j;
        int c = (i < N) ? cnt[i] : 0;
        loc[j] = c;
        sum += c;
    }
    s[t] = sum;
    __syncthreads();
    for (int off = 1; off < SCAN_T; off <<= 1) {
        int x = (t >= off) ? s[t - off] : 0;
        __syncthreads();
        s[t] += x;
        __syncthreads();
    }
    int run = bofs[b] + s[t] - sum;
#pragma unroll
    for (int j = 0; j < SCAN_CH; ++j) {
        int i = base + j;
        if (i < N) {
            rowptr[i] = run;
            run += loc[j];
        }
    }
    if (b == 0 && t == 0) rowptr[N] = E;
}

// ---- 2-level counting sort (bucket partition, line-dense writes) ----
__global__ __launch_bounds__(PART_T) void part_count_kernel(const int* __restrict__ ecol,
                                                            int* __restrict__ blockcnt, int E) {
    __shared__ int hist[NBUK];
    int b = blockIdx.x, t = threadIdx.x;
    for (int i = t; i < NBUK; i += PART_T) hist[i] = 0;
    __syncthreads();
    int CH = (E + NB_PART - 1) / NB_PART;
    int lo = b * CH;
    int hi = lo + CH; if (hi > E) hi = E;
    for (int e = lo + t; e < hi; e += PART_T)
        atomicAdd(&hist[ecol[e] >> BSHIFT], 1);
    __syncthreads();
    for (int i = t; i < NBUK; i += PART_T) blockcnt[i * NB_PART + b] = hist[i];
}

__global__ __launch_bounds__(NB_PART) void part_scan_kernel(const int* __restrict__ blockcnt,
                                                            int* __restrict__ boffrel,
                                                            int* __restrict__ buktot) {
    __shared__ int s[NB_PART];
    int k = blockIdx.x, t = threadIdx.x;
    int v = blockcnt[k * NB_PART + t];
    s[t] = v;
    __syncthreads();
    for (int off = 1; off < NB_PART; off <<= 1) {
        int x = (t >= off) ? s[t - off] : 0;
        __syncthreads();
        s[t] += x;
        __syncthreads();
    }
    boffrel[k * NB_PART + t] = s[t] - v;  // exclusive, bucket-relative
    if (t == NB_PART - 1) buktot[k] = s[t];
}

__global__ __launch_bounds__(256) void buk_scan_kernel(const int* __restrict__ buktot,
                                                       int* __restrict__ bukbase) {
    __shared__ int s[256];
    int t = threadIdx.x;
    int v = (t < NBUK) ? buktot[t] : 0;
    s[t] = v;
    __syncthreads();
    for (int off = 1; off < 256; off <<= 1) {
        int x = (t >= off) ? s[t - off] : 0;
        __syncthreads();
        s[t] += x;
        __syncthreads();
    }
    if (t < NBUK) bukbase[t] = s[t] - v;  // exclusive
}

__global__ __launch_bounds__(PART_T) void part_write_kernel(const int* __restrict__ erow,
                                                            const int* __restrict__ ecol,
                                                            const int* __restrict__ boffrel,
                                                            const int* __restrict__ bukbase,
                                                            unsigned int* __restrict__ staging, int E) {
    __shared__ int lofs[NBUK];
    int b = blockIdx.x, t = threadIdx.x;
    for (int i = t; i < NBUK; i += PART_T) lofs[i] = bukbase[i] + boffrel[i * NB_PART + b];
    __syncthreads();
    int CH = (E + NB_PART - 1) / NB_PART;
    int lo = b * CH;
    int hi = lo + CH; if (hi > E) hi = E;
    for (int e = lo + t; e < hi; e += PART_T) {
        int c = ecol[e], r = erow[e];
        int k = c >> BSHIFT;
        int pos = atomicAdd(&lofs[k], 1);
        staging[pos] = (unsigned)r | ((unsigned)(c & 511) << 20);
    }
}

__global__ __launch_bounds__(512) void buk_nodecount_kernel(const unsigned int* __restrict__ staging,
                                                            const int* __restrict__ bukbase,
                                                            const int* __restrict__ buktot,
                                                            int* __restrict__ cnt, int N) {
    __shared__ int hist[512];
    int k = blockIdx.x, t = threadIdx.x;
    hist[t] = 0;
    __syncthreads();
    int lo = bukbase[k];
    int hi = lo + buktot[k];
    for (int e = lo + t; e < hi; e += 512)
        atomicAdd(&hist[staging[e] >> 20], 1);
    __syncthreads();
    int node = (k << BSHIFT) + t;
    if (node < N) cnt[node] = hist[t];
}

__global__ __launch_bounds__(512) void part_scatter_kernel(const unsigned int* __restrict__ staging,
                                                           const int* __restrict__ rowptr,
                                                           int* __restrict__ srcs, int N, int E) {
    __shared__ int lnxt[512];
    int k = blockIdx.x, t = threadIdx.x;
    int base = k << BSHIFT;
    int node = base + t;
    lnxt[t] = (node < N) ? rowptr[node] : 0;
    __syncthreads();
    int estart = rowptr[base];
    int hiidx = base + 512; if (hiidx > N) hiidx = N;
    int eend = rowptr[hiidx];
    for (int e = estart + t; e < eend; e += 512) {
        unsigned v = staging[e];
        int p = atomicAdd(&lnxt[v >> 20], 1);
        srcs[p] = (int)(v & 0xFFFFFu);
    }
}

// ------------------------------------------------------------------
// bf16 conversion (n must be a multiple of 8)
__global__ void cvt_bf16_kernel(const float* __restrict__ in, unsigned short* __restrict__ out,
                                size_t n) {
    size_t i = ((size_t)blockIdx.x * blockDim.x + threadIdx.x) * 8;
    size_t stride = (size_t)gridDim.x * blockDim.x * 8;
    for (; i < n; i += stride) {
        float4 a = *(const float4*)(in + i);
        float4 b = *(const float4*)(in + i + 4);
        union { unsigned short u[8]; uint4 v; } r;
        r.u[0] = f2bf(a.x); r.u[1] = f2bf(a.y); r.u[2] = f2bf(a.z); r.u[3] = f2bf(a.w);
        r.u[4] = f2bf(b.x); r.u[5] = f2bf(b.y); r.u[6] = f2bf(b.z); r.u[7] = f2bf(b.w);
        *(uint4*)(out + i) = r.v;
    }
}

// W [K][N] f32 -> Wt [Npad][K] bf16 (transpose + convert, zero-pad rows)
__global__ void wt_cvt_kernel(const float* __restrict__ W, unsigned short* __restrict__ Wt,
                              int K, int N, int Npad) {
    int idx = blockIdx.x * blockDim.x + threadIdx.x;
    int total = Npad * K;
    if (idx >= total) return;
    int n = idx / K, k = idx - n * K;
    float v = (n < N) ? W[(size_t)k * N + n] : 0.f;
    Wt[idx] = f2bf(v);
}

// ------------------------------------------------------------------
// bf16 MFMA GEMM: C = act(A[M,K] @ Bt[N,K]^T + bias)
// FINAL=0: store bf16 C (ldc=N). FINAL=1: store fp16 h16 and u16=dis*h (ldc=64).
template <int RELU, int FINAL>
__global__ __launch_bounds__(256) void gemm_mfma_kernel(
    const unsigned short* __restrict__ A, const unsigned short* __restrict__ Bt,
    const float* __restrict__ bias, unsigned short* __restrict__ Cb,
    _Float16* __restrict__ h16out, _Float16* __restrict__ u16out, const float* __restrict__ dis,
    int M, int K, int N) {
    __shared__ unsigned short sA[128 * 64];
    __shared__ unsigned short sB[128 * 64];
    const int t = threadIdx.x;
    const int wid = t >> 6, lane = t & 63;
    const int bm = blockIdx.x * 128, bn = blockIdx.y * 128;
    const int wr = wid >> 1, wc = wid & 1;

    const int srow = lane >> 3;        // 0..7 row within 8-row group
    const int skb = (lane & 7) * 8;    // bf16-element offset within row (16B granules)

    f32x4 acc[4][4] = {};

    for (int k0 = 0; k0 < K; k0 += 64) {
#pragma unroll
        for (int j = 0; j < 4; ++j) {
            int rbase = (wid * 4 + j) * 8;
            int grow = bm + rbase + srow;
            if (grow >= M) grow = M - 1;
            const unsigned short* asrc = A + (size_t)grow * K + k0 + skb;
            __builtin_amdgcn_global_load_lds(
                (const __attribute__((address_space(1))) unsigned int*)asrc,
                (__attribute__((address_space(3))) unsigned int*)&sA[rbase * 64], 16, 0, 0);
            int gcol = bn + rbase + srow;  // Bt rows are output columns (allocated/padded)
            const unsigned short* bsrc = Bt + (size_t)gcol * K + k0 + skb;
            __builtin_amdgcn_global_load_lds(
                (const __attribute__((address_space(1))) unsigned int*)bsrc,
                (__attribute__((address_space(3))) unsigned int*)&sB[rbase * 64], 16, 0, 0);
        }
        __syncthreads();

        const int fr = lane & 15;
        const int fk = (lane >> 4) * 8;
#pragma unroll
        for (int ks = 0; ks < 2; ++ks) {
            bf16x8 af[4], bfr[4];
#pragma unroll
            for (int m = 0; m < 4; ++m)
                af[m] = *(const bf16x8*)&sA[(wr * 64 + m * 16 + fr) * 64 + ks * 32 + fk];
#pragma unroll
            for (int n = 0; n < 4; ++n)
                bfr[n] = *(const bf16x8*)&sB[(wc * 64 + n * 16 + fr) * 64 + ks * 32 + fk];
#pragma unroll
            for (int m = 0; m < 4; ++m)
#pragma unroll
                for (int n = 0; n < 4; ++n)
                    acc[m][n] = __builtin_amdgcn_mfma_f32_16x16x32_bf16(af[m], bfr[n], acc[m][n], 0, 0, 0);
        }
        __syncthreads();
    }

    const int fr = lane & 15, fq = (lane >> 4) * 4;
#pragma unroll
    for (int m = 0; m < 4; ++m) {
#pragma unroll
        for (int n = 0; n < 4; ++n) {
            int col = bn + wc * 64 + n * 16 + fr;
            if (col >= N) continue;
            float bv = bias[col];
#pragma unroll
            for (int q = 0; q < 4; ++q) {
                int r = bm + wr * 64 + m * 16 + fq + q;
                if (r >= M) continue;
                float v = acc[m][n][q] + bv;
                if (RELU) v = fmaxf(v, 0.f);
                if (!FINAL) {
                    Cb[(size_t)r * N + col] = f2bf(v);
                } else {
                    h16out[(size_t)r * 64 + col] = (_Float16)v;
                    u16out[(size_t)r * 64 + col] = (_Float16)(dis[r] * v);
                }
            }
        }
    }
}

// ------------------------------------------------------------------
// fp32 fallback GEMM (proven): C = act(A@B + bias)
template <int RELU>
__global__ __launch_bounds__(256) void gemm_bias_kernel(
    const float* __restrict__ A, const float* __restrict__ B,
    const float* __restrict__ bias, float* __restrict__ C,
    int M, int K, int N) {
    __shared__ float sA[16][64];
    __shared__ float sB[16][64];
    const int bm = blockIdx.x * 64;
    const int bn = blockIdx.y * 64;
    const int t = threadIdx.x;
    const int tx = t & 15, ty = t >> 4;
    const int arow_l = t >> 2;
    const int akk = (t & 3) * 4;
    const int brow = t >> 4;
    const int bcol = (t & 15) * 4;
    float acc[4][4] = {};

    for (int k0 = 0; k0 < K; k0 += 16) {
        float4 av = make_float4(0.f, 0.f, 0.f, 0.f);
        int arow = bm + arow_l;
        if (arow < M) av = *(const float4*)(A + (size_t)arow * K + k0 + akk);
        float4 bv = *(const float4*)(B + (size_t)(k0 + brow) * N + bn + bcol);
        sA[akk + 0][arow_l] = av.x;
        sA[akk + 1][arow_l] = av.y;
        sA[akk + 2][arow_l] = av.z;
        sA[akk + 3][arow_l] = av.w;
        *(float4*)&sB[brow][bcol] = bv;
        __syncthreads();
#pragma unroll
        for (int k = 0; k < 16; ++k) {
            float4 a4 = *(const float4*)&sA[k][ty * 4];
            float4 b4 = *(const float4*)&sB[k][tx * 4];
            acc[0][0] += a4.x * b4.x; acc[0][1] += a4.x * b4.y; acc[0][2] += a4.x * b4.z; acc[0][3] += a4.x * b4.w;
            acc[1][0] += a4.y * b4.x; acc[1][1] += a4.y * b4.y; acc[1][2] += a4.y * b4.z; acc[1][3] += a4.y * b4.w;
            acc[2][0] += a4.z * b4.x; acc[2][1] += a4.z * b4.y; acc[2][2] += a4.z * b4.z; acc[2][3] += a4.z * b4.w;
            acc[3][0] += a4.w * b4.x; acc[3][1] += a4.w * b4.y; acc[3][2] += a4.w * b4.z; acc[3][3] += a4.w * b4.w;
        }
        __syncthreads();
    }

#pragma unroll
    for (int i = 0; i < 4; ++i) {
        int row = bm + ty * 4 + i;
        if (row >= M) continue;
#pragma unroll
        for (int j = 0; j < 4; ++j) {
            int colg = bn + tx * 4 + j;
            float v = acc[i][j] + bias[colg];
            if (RELU) v = fmaxf(v, 0.f);
            C[(size_t)row * N + colg] = v;
        }
    }
}

// fallback: h fp32 -> h16, u16 = dis*h
__global__ void h16u0_kernel(const float* __restrict__ h, const float* __restrict__ dis,
                             _Float16* __restrict__ h16, _Float16* __restrict__ u16, int total) {
    int i = blockIdx.x * blockDim.x + threadIdx.x;
    if (i < total) {
        float v = h[i];
        h16[i] = (_Float16)v;
        u16[i] = (_Float16)(dis[i >> 6] * v);
    }
}

// ------------------------------------------------------------------
// APPNP step on u = dis*z (fp16 state, packed fp16 accumulate).
// Edge-group mapping is BLOCKED-BY-4: group g owns contiguous quad
// [g*4, g*4+4) of each 32-edge block -> 4 contiguous srcs reads (1 line)
// and 4 INDEPENDENT u-row gathers in flight per wave.
//   S = sum_e u[src];  z' = 0.8*d*(S + u[n]) + 0.2*h
// FINAL=0 stores u' = d*z' (fp16); FINAL=1 stores z' (fp32 out).
template <int FINAL>
__global__ __launch_bounds__(256) void appnp_step16_kernel(
    const int* __restrict__ rowptr, const int* __restrict__ srcs,
    const float* __restrict__ dis, const _Float16* __restrict__ uin,
    const _Float16* __restrict__ hbuf, void* __restrict__ outbuf, int N) {
    int node = blockIdx.x * 4 + (threadIdx.x >> 6);
    if (node >= N) return;
    int lane = threadIdx.x & 63;
    int eg = lane >> 3;   // edge group 0..7
    int fl = lane & 7;    // 8-half chunk index (64 feats)

    int start = rowptr[node];
    int end = rowptr[node + 1];

    // hoist epilogue operands (latency hides under the edge loop/reduce)
    float d = dis[node];
    f16x8 us = *(const f16x8*)(uin + (size_t)node * 64 + fl * 8);
    f16x8 hv = *(const f16x8*)(hbuf + (size_t)node * 64 + fl * 8);

    f16x8 a0 = {}, a1 = {}, a2 = {}, a3 = {};
    int deg = end - start;
    int nfull = deg >> 5;            // full 32-edge blocks
    int e = start + (eg << 2);
    for (int b = 0; b < nfull; ++b, e += 32) {
        int s0 = srcs[e + 0];
        int s1 = srcs[e + 1];
        int s2 = srcs[e + 2];
        int s3 = srcs[e + 3];
        f16x8 z0 = *(const f16x8*)(uin + (size_t)s0 * 64 + fl * 8);
        f16x8 z1 = *(const f16x8*)(uin + (size_t)s1 * 64 + fl * 8);
        f16x8 z2 = *(const f16x8*)(uin + (size_t)s2 * 64 + fl * 8);
        f16x8 z3 = *(const f16x8*)(uin + (size_t)s3 * 64 + fl * 8);
        a0 += z0; a1 += z1; a2 += z2; a3 += z3;
    }
    // tail: remaining edges, stride-8 interleaved
    for (int e2 = start + (nfull << 5) + eg; e2 < end; e2 += 8) {
        int s0 = srcs[e2];
        a0 += *(const f16x8*)(uin + (size_t)s0 * 64 + fl * 8);
    }
    a0 += a1; a2 += a3; a0 += a2;

    // packed reduce across the 8 edge groups
    union { f16x8 h; unsigned int w[4]; } uacc, uoth;
    uacc.h = a0;
#pragma unroll
    for (int m = 8; m <= 32; m <<= 1) {
#pragma unroll
        for (int j = 0; j < 4; ++j) uoth.w[j] = __shfl_xor(uacc.w[j], m);
        uacc.h += uoth.h;
    }

    if (eg == 0) {
        float o[8];
#pragma unroll
        for (int j = 0; j < 8; ++j)
            o[j] = 0.8f * d * ((float)uacc.h[j] + (float)us[j]) + 0.2f * (float)hv[j];
        if (FINAL) {
            float* op = (float*)outbuf + (size_t)node * 64 + fl * 8;
            *(float4*)op = make_float4(o[0], o[1], o[2], o[3]);
            *(float4*)(op + 4) = make_float4(o[4], o[5], o[6], o[7]);
        } else {
            f16x8 ov;
#pragma unroll
            for (int j = 0; j < 8; ++j) ov[j] = (_Float16)(d * o[j]);
            *(f16x8*)((_Float16*)outbuf + (size_t)node * 64 + fl * 8) = ov;
        }
    }
}

// ------------------------------------------------------------------
extern "C" void kernel_launch(void* const* d_in, const int* in_sizes, int n_in,
                              void* d_out, int out_size, void* d_ws, size_t ws_size,
                              hipStream_t stream) {
    const float* x  = (const float*)d_in[0];
    const int*   ei = (const int*)d_in[1];
    const float* W0 = (const float*)d_in[2];
    const float* b0 = (const float*)d_in[3];
    const float* W1 = (const float*)d_in[4];
    const float* b1 = (const float*)d_in[5];
    const float* W2 = (const float*)d_in[6];
    const float* b2 = (const float*)d_in[7];
    float* out = (float*)d_out;

    const int N = NN;
    const int E = in_sizes[1] / 2;
    const int* erow = ei;       // sources
    const int* ecol = ei + E;   // targets
    (void)out_size; (void)n_in;

    char* ws = (char*)d_ws;
    size_t off = 0;
    auto alloc = [&](size_t bytes) -> void* {
        void* p = ws + off;
        off += (bytes + 255) & ~(size_t)255;
        return p;
    };
    // common
    int*   cnt      = (int*)alloc((size_t)N * 4);
    int*   rowptr   = (int*)alloc((size_t)(N + 1) * 4);
    float* dis      = (float*)alloc((size_t)N * 4);
    int*   bsum     = (int*)alloc((size_t)SCAN_B * 4);
    int*   bofs     = (int*)alloc((size_t)SCAN_B * 4);
    int*   blockcnt = (int*)alloc((size_t)NBUK * NB_PART * 4);
    int*   boffrel  = (int*)alloc((size_t)NBUK * NB_PART * 4);
    int*   buktot   = (int*)alloc((size_t)NBUK * 4);
    int*   bukbase  = (int*)alloc((size_t)NBUK * 4);
    unsigned int* staging = (unsigned int*)alloc((size_t)E * 4);
    int*   srcs     = (int*)alloc((size_t)E * 4);
    _Float16* h16 = (_Float16*)alloc((size_t)N * 64 * 2);
    _Float16* ua  = (_Float16*)alloc((size_t)N * 64 * 2);
    _Float16* ub  = (_Float16*)alloc((size_t)N * 64 * 2);
    size_t common_end = off;

    // bf16-path extra
    size_t need_bf16 = common_end
        + (((size_t)N * 512 * 2 + 255) & ~(size_t)255)     // xb
        + ((256 * 512 * 2 + 255) & ~(size_t)255)           // Wt0
        + ((256 * 256 * 2 + 255) & ~(size_t)255)           // Wt1
        + ((128 * 256 * 2 + 255) & ~(size_t)255)           // Wt2 (padded)
        + (((size_t)N * 256 * 2 + 255) & ~(size_t)255)     // h1b
        + (((size_t)N * 256 * 2 + 255) & ~(size_t)255);    // h2b
    const bool use_bf16 = (ws_size >= need_bf16 + (1u << 20));

    // ---- 2-level counting sort into CSC (no global atomics on hot paths) ----
    part_count_kernel<<<NB_PART, PART_T, 0, stream>>>(ecol, blockcnt, E);
    part_scan_kernel<<<NBUK, NB_PART, 0, stream>>>(blockcnt, boffrel, buktot);
    buk_scan_kernel<<<1, 256, 0, stream>>>(buktot, bukbase);
    part_write_kernel<<<NB_PART, PART_T, 0, stream>>>(erow, ecol, boffrel, bukbase, staging, E);
    buk_nodecount_kernel<<<NBUK, 512, 0, stream>>>(staging, bukbase, buktot, cnt, N);
    dis_kernel<<<(N + 255) / 256, 256, 0, stream>>>(cnt, dis, N);
    scan_part_kernel<<<SCAN_B, SCAN_T, 0, stream>>>(cnt, bsum, N);
    scan_bsum_kernel<<<1, SCAN_B, 0, stream>>>(bsum, bofs);
    scan_write_kernel<<<SCAN_B, SCAN_T, 0, stream>>>(cnt, bofs, rowptr, N, E);
    part_scatter_kernel<<<NBUK, 512, 0, stream>>>(staging, rowptr, srcs, N, E);

    // ---- MLP -> h16 (fp16) and ua = u0 = dis*h (fp16) ----
    if (use_bf16) {
        unsigned short* xb  = (unsigned short*)alloc((size_t)N * 512 * 2);
        unsigned short* Wt0 = (unsigned short*)alloc(256 * 512 * 2);
        unsigned short* Wt1 = (unsigned short*)alloc(256 * 256 * 2);
        unsigned short* Wt2 = (unsigned short*)alloc(128 * 256 * 2);
        unsigned short* h1b = (unsigned short*)alloc((size_t)N * 256 * 2);
        unsigned short* h2b = (unsigned short*)alloc((size_t)N * 256 * 2);

        cvt_bf16_kernel<<<2048, 256, 0, stream>>>(x, xb, (size_t)N * 512);
        wt_cvt_kernel<<<(256 * 512 + 255) / 256, 256, 0, stream>>>(W0, Wt0, 512, 256, 256);
        wt_cvt_kernel<<<(256 * 256 + 255) / 256, 256, 0, stream>>>(W1, Wt1, 256, 256, 256);
        wt_cvt_kernel<<<(128 * 256 + 255) / 256, 256, 0, stream>>>(W2, Wt2, 256, 64, 128);

        const int gm = (N + 127) / 128;  // 782
        dim3 g0(gm, 2);
        gemm_mfma_kernel<1, 0><<<g0, 256, 0, stream>>>(xb, Wt0, b0, h1b, nullptr, nullptr, nullptr, N, 512, 256);
        gemm_mfma_kernel<1, 0><<<g0, 256, 0, stream>>>(h1b, Wt1, b1, h2b, nullptr, nullptr, nullptr, N, 256, 256);
        dim3 g2(gm, 1);
        gemm_mfma_kernel<0, 1><<<g2, 256, 0, stream>>>(h2b, Wt2, b2, nullptr, h16, ua, dis, N, 256, 64);
    } else {
        const int Ms = 12500;
        float* hf  = (float*)alloc((size_t)N * 64 * 4);
        float* h1s = (float*)alloc((size_t)Ms * 256 * 4);
        float* h2s = (float*)alloc((size_t)Ms * 256 * 4);
        for (int s0 = 0; s0 < N; s0 += Ms) {
            int rows = (N - s0 < Ms) ? (N - s0) : Ms;
            dim3 g1((rows + 63) / 64, 4);
            gemm_bias_kernel<1><<<g1, 256, 0, stream>>>(x + (size_t)s0 * 512, W0, b0, h1s, rows, 512, 256);
            gemm_bias_kernel<1><<<g1, 256, 0, stream>>>(h1s, W1, b1, h2s, rows, 256, 256);
            dim3 g3((rows + 63) / 64, 1);
            gemm_bias_kernel<0><<<g3, 256, 0, stream>>>(h2s, W2, b2, hf + (size_t)s0 * 64, rows, 256, 64);
        }
        h16u0_kernel<<<(N * 64 + 255) / 256, 256, 0, stream>>>(hf, dis, h16, ua, N * 64);
    }

    // ---- APPNP propagation: 10 steps on u (fp16, packed + 4-way MLP) ----
    const _Float16* uin = ua;
    for (int k = 0; k < 10; ++k) {
        if (k == 9) {
            appnp_step16_kernel<1><<<(N + 3) / 4, 256, 0, stream>>>(rowptr, srcs, dis, uin, h16, out, N);
        } else {
            _Float16* uout = (k & 1) ? ua : ub;
            appnp_step16_kernel<0><<<(N + 3) / 4, 256, 0, stream>>>(rowptr, srcs, dis, uin, h16, uout, N);
            uin = uout;
        }
    }
}